// Round 12
// baseline (1361.220 us; speedup 1.0000x reference)
//
#include <hip/hip_runtime.h>
#include <stdint.h>

// ============================================================================
// Reformer/LSH iTransformer forward on MI355X (gfx950). ALL I/O FP32.
// R20 = R19 + XCD-chunked block swizzle in k_gemm (T1, bijective m204 form):
// flat id -> f2 = x*q + min(x,r) + j (x=flat&7, j=flat>>3) so each XCD's
// private L2 sees a CONTIGUOUS run of row-panels with all their column
// blocks. R19 profile: c2 FETCH=138MB vs ~72MB ideal (4 col-blocks of one
// A-panel land on 4 XCDs -> per-L2 re-fetch), dur 103.7us = traffic/1.7TB/s.
// Pure scheduling change -> absmax must stay EXACTLY 0.01171875 (falsifier).
// History: R14 -192 (0.0117), R16 -103 (0.0156), R17 -61 (0.0117),
//          R18 -26 (0.0117 bit-id), R19 -36 (0.0117 bit-id, unchunked FFN).
// ============================================================================

constexpr int B_=32, L_=512, E_=512, NMARK_=4, D_=512, DFF_=2048, NLAYERS_=2;
constexpr int NTOK=516, TPAD=520, DH_=64, NB_=130, NHASH_=4;
constexpr int BH_=256, NCH_=520;

typedef __attribute__((ext_vector_type(8))) short v8s;
typedef __attribute__((ext_vector_type(4))) float v4f;

typedef __attribute__((address_space(1))) const unsigned int gu32;
typedef __attribute__((address_space(3))) unsigned int lu32;
static __device__ __forceinline__ void gload_lds16(const void* g, void* l){
  __builtin_amdgcn_global_load_lds((gu32*)g, (lu32*)l, 16, 0, 0);
}

static __device__ __forceinline__ unsigned short f2bf(float f){
  union{float f; unsigned int u;} c; c.f=f;
  unsigned int u=c.u;
  return (unsigned short)((u + 0x7fffu + ((u>>16)&1u))>>16);  // RNE
}
static __device__ __forceinline__ float bf2f(unsigned short h){
  union{unsigned int u; float f;} c; c.u=((unsigned int)h)<<16; return c.f;
}
static __device__ __forceinline__ float blockReduce256(float v, float* red, int tid){
  for(int o=32;o;o>>=1) v += __shfl_down(v,o,64);
  __syncthreads();
  if((tid&63)==0) red[tid>>6]=v;
  __syncthreads();
  return red[0]+red[1]+red[2]+red[3];
}

// ---------------- generic fp32 -> (hi,lo) bf16 split ------------------------
__global__ void k_split(const float* __restrict__ src, unsigned short* __restrict__ hi,
    unsigned short* __restrict__ lo, int n){
  int idx=blockIdx.x*256+threadIdx.x;
  if(idx>=n) return;
  float v=src[idx];
  unsigned short h=f2bf(v);
  hi[idx]=h; lo[idx]=f2bf(v-bf2f(h));
}

// ---------------- RevIN stats over L per (b,e) ------------------------------
__global__ __launch_bounds__(256) void k_revin(const float* __restrict__ xe,
    float* __restrict__ means, float* __restrict__ stdev){
  int b=blockIdx.y;
  int e=blockIdx.x*256+threadIdx.x;
  const float* p = xe + (size_t)b*L_*E_ + e;
  float s=0.f,s2=0.f;
  for(int l=0;l<L_;l++){ float v=p[(size_t)l*E_]; s+=v; s2+=v*v; }
  float m=s*(1.f/512.f);
  float var=s2*(1.f/512.f)-m*m;
  var = var>0.f? var:0.f;
  means[b*E_+e]=m;
  stdev[b*E_+e]=sqrtf(var+1e-5f);
}

// ------- transpose x_enc -> token rows with RevIN, split-write hi/lo --------
__global__ __launch_bounds__(256) void k_pack_tok(const float* __restrict__ xe,
     const float* __restrict__ means, const float* __restrict__ stdev,
     unsigned short* __restrict__ hi, unsigned short* __restrict__ lo){
  __shared__ float tile[64][65];
  int b=blockIdx.z;
  int ct=blockIdx.x*64, lt=blockIdx.y*64;
  int tid=threadIdx.x;
  int i=tid>>2, j0=(tid&3)*16;
  {
    const float* src = xe + ((size_t)b*L_ + lt + i)*E_ + ct + j0;
    float tmp[16];
    *(float4*)&tmp[0]  = *(const float4*)(src);
    *(float4*)&tmp[4]  = *(const float4*)(src+4);
    *(float4*)&tmp[8]  = *(const float4*)(src+8);
    *(float4*)&tmp[12] = *(const float4*)(src+12);
    for(int j=0;j<16;j++) tile[i][j0+j]=tmp[j];
  }
  __syncthreads();
  {
    float ms=means[b*E_+ct+i];
    float sd=stdev[b*E_+ct+i];
    unsigned short hs[16], ls[16];
    for(int j=0;j<16;j++){
      float v=(tile[j0+j][i]-ms)/sd;
      unsigned short hh=f2bf(v);
      hs[j]=hh; ls[j]=f2bf(v-bf2f(hh));
    }
    size_t off = ((size_t)b*NTOK + ct + i)*(size_t)L_ + lt + j0;
    *(uint4*)&hi[off]   = *(uint4*)&hs[0];
    *(uint4*)&hi[off+8] = *(uint4*)&hs[8];
    *(uint4*)&lo[off]   = *(uint4*)&ls[0];
    *(uint4*)&lo[off+8] = *(uint4*)&ls[8];
  }
}

__global__ void k_pack_marks(const float* __restrict__ xm,
    unsigned short* __restrict__ hi, unsigned short* __restrict__ lo){
  int idx=blockIdx.x*256+threadIdx.x; // 32*4*512
  int l=idx&511, j=(idx>>9)&3, b=idx>>11;
  float v = xm[((size_t)b*L_ + l)*NMARK_ + j];
  unsigned short hh=f2bf(v);
  size_t off=((size_t)b*NTOK + E_ + j)*(size_t)L_ + l;
  hi[off]=hh; lo[off]=f2bf(v-bf2f(hh));
}

// ------ 128x128 bf16 MFMA GEMM, 48 KB LDS both variants -> 3 blk/CU ---------
// XCD-chunked block swizzle: f2 = x*q+min(x,r)+j gives each XCD a contiguous
// run of row-panels (all col-blocks included) -> A-panel L2 locality.
// AFULL=true : hi tiles double-buffered, lo tiles single-buffered (2 barriers
//              per iter); 3 MFMAs. BIT-identical math to the 64KB scheme.
// AFULL=false: 3 tiles double-buffered; 2 MFMAs.
// OUTMODE 0: fp32 C. 3: relu + bf16-hi only.
// TPADDED: M rows indexed b*520+t, A from compact [b*516+t], t>=516 -> zeropad.
template<int OUTMODE, bool TPADDED, bool AFULL>
__global__ __launch_bounds__(256) void k_gemm(
    const unsigned short* __restrict__ Ahi, const unsigned short* __restrict__ Alo,
    const unsigned short* __restrict__ Bhi, const unsigned short* __restrict__ Blo,
    const float* __restrict__ bias, float* __restrict__ Cf,
    unsigned short* __restrict__ Chi, unsigned short* __restrict__ Clo,
    const unsigned short* __restrict__ zeropad,
    int M, int N, int K)
{
  __shared__ __align__(16) unsigned short LDS[6][128*32];   // 48 KB
  // ---- XCD-chunked swizzle (bijective, any grid size; m204 form) ----
  int flat = blockIdx.y*gridDim.x + blockIdx.x;
  int ntot = gridDim.x*gridDim.y;
  int q = ntot>>3, r = ntot&7;
  int xcd = flat&7, jj = flat>>3;
  int f2 = xcd*q + (xcd<r?xcd:r) + jj;
  const int m0=(f2/(int)gridDim.x)*128, n0=(f2%(int)gridDim.x)*128;
  const int tid=threadIdx.x, lane=tid&63, wave=tid>>6;
  const int wm=(wave>>1)*64, wn=(wave&1)*64;

  // wave->tile: AFULL: 0=Ahi 1=Alo 2=Bhi 3=Blo ; else: 0=Ahi 1=Bhi 2=Blo.
  // call j covers rows j*16..j*16+15; lane i -> row j*16+(i>>2), 16B seg (i&3).
  const unsigned short* srcp;
  bool isA;
  if constexpr (AFULL){
    srcp = (wave==0)?Ahi:(wave==1)?Alo:(wave==2)?Bhi:Blo;
    isA  = (wave<2);
  } else {
    srcp = (wave==0)?Ahi:(wave==1)?Bhi:Blo;   // wave 3 idles
    isA  = (wave==0);
  }
  const bool stager = AFULL || (wave<3);
  const int rsub=lane>>2, seg=(lane&3)*8;
  const unsigned short* gp[8]; int stp[8];
  #pragma unroll
  for(int j=0;j<8;j++){
    int row=j*16+rsub;
    if(isA){
      size_t ao; bool valid=true;
      int g=m0+row;
      if constexpr (TPADDED){
        int b=g/TPAD; int t=g-b*TPAD; valid=(t<NTOK);
        ao=((size_t)b*NTOK + (valid?t:0))*(size_t)K;
      } else ao=(size_t)g*(size_t)K;
      gp[j]= valid ? (srcp+ao+seg) : (zeropad+seg);
      stp[j]= valid ? 32 : 0;
    } else {
      gp[j]= srcp + (size_t)(n0+row)*(size_t)K + seg;
      stp[j]=32;
    }
  }

  v4f acc[4][4];
  for(int i=0;i<4;i++)for(int j=0;j<4;j++) acc[i][j]=(v4f){0.f,0.f,0.f,0.f};
  const int am = wm + (lane&15);
  const int bn = wn + (lane&15);
  const int kk = (lane>>4)*8;
  const int nIter=K/32;

  if constexpr (AFULL){
    // prologue: wave0->Ahi buf0 (LDS0), wave2->Bhi buf0 (LDS1),
    //           wave1->Alo (LDS4), wave3->Blo (LDS5)
    {
      unsigned short* dst0 = (wave==0)?&LDS[0][0]:(wave==2)?&LDS[1][0]
                            :(wave==1)?&LDS[4][0]:&LDS[5][0];
      #pragma unroll
      for(int j=0;j<8;j++){ gload_lds16(gp[j], dst0+j*512); gp[j]+=stp[j]; }
    }
    for(int k=0;k<nIter;k++){
      __syncthreads();   // drains: hi buf[k&1] + lo(k) complete
      if(k+1<nIter && (wave==0||wave==2)){   // hi prefetch overlaps MFMAs
        unsigned short* nxt=&LDS[((k+1)&1)*2+(wave>>1)][0];
        #pragma unroll
        for(int j=0;j<8;j++){ gload_lds16(gp[j], nxt+j*512); gp[j]+=stp[j]; }
      }
      const unsigned short* curA =&LDS[(k&1)*2+0][0];
      const unsigned short* curB =&LDS[(k&1)*2+1][0];
      const unsigned short* curAl=&LDS[4][0];
      const unsigned short* curBl=&LDS[5][0];
      v8s a[4], al[4], b[4], bl[4];
      for(int t=0;t<4;t++){
        a[t] =*(const v8s*)&curA [(am+t*16)*32+kk];
        al[t]=*(const v8s*)&curAl[(am+t*16)*32+kk];
        b[t] =*(const v8s*)&curB [(bn+t*16)*32+kk];
        bl[t]=*(const v8s*)&curBl[(bn+t*16)*32+kk];
      }
      for(int mt=0;mt<4;mt++)for(int nt=0;nt<4;nt++){
        acc[mt][nt]=__builtin_amdgcn_mfma_f32_16x16x32_bf16(al[mt],b[nt], acc[mt][nt],0,0,0);
        acc[mt][nt]=__builtin_amdgcn_mfma_f32_16x16x32_bf16(a[mt], bl[nt],acc[mt][nt],0,0,0);
        acc[mt][nt]=__builtin_amdgcn_mfma_f32_16x16x32_bf16(a[mt], b[nt], acc[mt][nt],0,0,0);
      }
      if(k+1<nIter){     // k uniform -> barrier uniform
        __syncthreads(); // all waves done READING lo(k)
        if(wave==1||wave==3){   // re-stage lo(k+1) into the single buffer
          unsigned short* nxt=&LDS[4+(wave>>1)][0];
          #pragma unroll
          for(int j=0;j<8;j++){ gload_lds16(gp[j], nxt+j*512); gp[j]+=stp[j]; }
        }
      }
    }
  } else {
    // prologue: DMA tile 0 into buf 0 (tiles = LDS[buf*3 + {0,1,2}])
    if(stager){
      #pragma unroll
      for(int j=0;j<8;j++){ gload_lds16(gp[j], &LDS[wave][j*512]); gp[j]+=stp[j]; }
    }
    for(int k=0;k<nIter;k++){
      __syncthreads();   // buf[k&1] DMA complete
      if(k+1<nIter && stager){
        unsigned short* nxt=&LDS[((k+1)&1)*3+wave][0];
        #pragma unroll
        for(int j=0;j<8;j++){ gload_lds16(gp[j], nxt+j*512); gp[j]+=stp[j]; }
      }
      const unsigned short* curA =&LDS[(k&1)*3+0][0];
      const unsigned short* curB =&LDS[(k&1)*3+1][0];
      const unsigned short* curBl=&LDS[(k&1)*3+2][0];
      v8s a[4], b[4], bl[4];
      for(int t=0;t<4;t++){
        a[t] =*(const v8s*)&curA [(am+t*16)*32+kk];
        b[t] =*(const v8s*)&curB [(bn+t*16)*32+kk];
        bl[t]=*(const v8s*)&curBl[(bn+t*16)*32+kk];
      }
      for(int mt=0;mt<4;mt++)for(int nt=0;nt<4;nt++){
        acc[mt][nt]=__builtin_amdgcn_mfma_f32_16x16x32_bf16(a[mt], bl[nt],acc[mt][nt],0,0,0);
        acc[mt][nt]=__builtin_amdgcn_mfma_f32_16x16x32_bf16(a[mt], b[nt], acc[mt][nt],0,0,0);
      }
    }
  }
  // C/D mapping: col=lane&15, row=(lane>>4)*4+r
  for(int mt=0;mt<4;mt++)for(int nt=0;nt<4;nt++){
    int col = n0 + wn + nt*16 + (lane&15);
    int rb  = m0 + wm + mt*16 + (lane>>4)*4;
    float bv = bias ? bias[col] : 0.f;
    for(int r2=0;r2<4;r2++){
      float v = acc[mt][nt][r2] + bv;
      size_t off=(size_t)(rb+r2)*N + col;
      if constexpr (OUTMODE==0){
        Cf[off]=v;
      } else {                            // OUTMODE==3: relu + hi-only bf16
        v = v>0.f ? v : 0.f;
        Chi[off]=f2bf(v);
      }
    }
  }
  (void)Clo;
}

// --- rot[f][h][i] (64 x 4 x 65) -> rT[h][tile][f][16] (i = tile*13+j, j<13) -
__global__ void k_rotTile(const float* __restrict__ rot, float* __restrict__ rT){
  int idx=blockIdx.x*256+threadIdx.x;   // 2 layers x 16640
  if(idx>=2*64*260) return;
  int lyr=idx/16640, r2=idx-lyr*16640;
  int f=r2/260, r=r2-f*260;             // r = h*65+i
  int h=r/65, i=r-h*65;
  int tile=i/13, j=i-tile*13;
  rT[(size_t)lyr*20800 + (((size_t)(h*5+tile)*64)+f)*16 + j]=rot[idx];
}

// ---------------- LSH buckets: wave=hash, thread=token, 5x13 output tiles ---
// (R13 version, best measured: 89us, VGPR 20, no spill.)
__global__ __launch_bounds__(256) void k_buckets(const float* __restrict__ qk,
    const float* __restrict__ rT, unsigned char* __restrict__ buckets){
  __shared__ float qkT[64*69];   // [f][t], stride 69 -> conflict-free
  int bh=blockIdx.x, tc=blockIdx.y;
  int b=bh>>3, hd=bh&7;
  int t0=tc*64;
  int tid=threadIdx.x;
  for(int j=tid;j<4096;j+=256){
    int t=j>>6, f=j&63;
    int tg=t0+t;
    qkT[f*69+t] = (tg<TPAD)? qk[((size_t)b*TPAD+tg)*(size_t)D_ + hd*64 + f] : 0.f;
  }
  __syncthreads();
  int h = __builtin_amdgcn_readfirstlane(tid>>6);   // wave-uniform hash
  int t = tid&63;
  float bv=-1.f; int bi=0x7fffffff;                 // cv >= 0 always
  #pragma unroll 1
  for(int tile=0; tile<5; ++tile){
    const float* rr = rT + ((size_t)(h*5+tile)*64)*16;  // wave-uniform
    float acc[13];
    #pragma unroll
    for(int j=0;j<13;j++) acc[j]=0.f;
    #pragma unroll 2
    for(int f=0;f<64;f++){
      float q = qkT[f*69+t];
      const float* rf = rr + f*16;
      #pragma unroll
      for(int j=0;j<13;j++) acc[j] += q*rf[j];
    }
    #pragma unroll
    for(int j=0;j<13;j++){
      int i = tile*13+j;
      float r=acc[j]; float cv; int ci;
      if(r>=-r){cv=r;ci=i;}else{cv=-r;ci=i+65;}
      if(cv>bv||(cv==bv&&ci<bi)){bv=cv;bi=ci;}
    }
  }
  int tg=t0+t;
  if(tg<TPAD) buckets[((size_t)bh*4+h)*TPAD+tg]=(unsigned char)bi;
}

// ---------------- stable counting sort == jnp.argsort(bucket*t+pos) ---------
__global__ __launch_bounds__(64) void k_sort(const unsigned char* __restrict__ buckets,
    unsigned short* __restrict__ sticker, unsigned short* __restrict__ undo){
  __shared__ int cnt[520];
  __shared__ int offs[520];
  int bh=blockIdx.x, tid=threadIdx.x;
  const unsigned char* bb = buckets + (size_t)bh*4*TPAD;
  for(int i=tid;i<520;i+=64) cnt[i]=0;
  __syncthreads();
  for(int i=tid;i<2080;i+=64){
    int h=i/TPAD;
    atomicAdd(&cnt[(int)bb[i]+h*NB_],1);
  }
  __syncthreads();
  if(tid==0){ int s=0; for(int k2=0;k2<520;k2++){ offs[k2]=s; s+=cnt[k2]; } }
  __syncthreads();
  if(tid<4){
    int h=tid;
    unsigned short* stk = sticker + (size_t)bh*2080;
    unsigned short* ud  = undo    + (size_t)bh*2080;
    for(int p=0;p<TPAD;p++){
      int key = (int)bb[h*TPAD+p] + h*NB_;
      int j = offs[key]++;
      stk[j] = (unsigned short)(h*TPAD+p);
      ud[h*TPAD+p] = (unsigned short)j;
    }
  }
}

// -------- attention pass 1: per-chunk LSE + store masked dots into PR -------
__global__ __launch_bounds__(256) void k_attn1(const float* __restrict__ qk,
    const unsigned short* __restrict__ sticker, float* __restrict__ lse,
    float* __restrict__ PR){
  __shared__ float rows[8][8][68];
  __shared__ int   sts[8][8];
  __shared__ float n2s[8][8];
  int tid=threadIdx.x, grp=tid>>5, lane=tid&31;
  int gid=blockIdx.x*8+grp;
  int bh=gid/NCH_, c=gid-bh*NCH_;
  int b=bh>>3, hd=bh&7;
  const unsigned short* stk = sticker + (size_t)bh*2080;
  if(lane<8){
    int r=lane;
    int cprev=(c+NCH_-1)%NCH_;
    int j=(r<4)? c*4+r : cprev*4+(r-4);
    sts[grp][r]=(int)stk[j]%TPAD;
  }
  __syncthreads();
  #pragma unroll
  for(int it=0; it<2; it++){
    int j=lane+32*it;
    int r=j>>3, f0=(j&7)*8;
    const float* src=qk+((size_t)b*TPAD+sts[grp][r])*(size_t)D_+hd*64+f0;
    *(float4*)&rows[grp][r][f0]   = *(const float4*)src;
    *(float4*)&rows[grp][r][f0+4] = *(const float4*)(src+4);
  }
  __syncthreads();
  {
    int r=lane>>2, part=lane&3;
    float s=0.f;
    #pragma unroll
    for(int f=part*16; f<part*16+16; f++){ float v=rows[grp][r][f]; s+=v*v; }
    s+=__shfl_xor(s,1,64); s+=__shfl_xor(s,2,64);
    if(part==0) n2s[grp][r]=s;
  }
  __syncthreads();
  int qi=lane>>3, kj=lane&7;
  float dt=0.f;
  #pragma unroll
  for(int f=0;f<64;f++) dt += rows[grp][qi][f]*rows[grp][kj][f];
  float kn=n2s[grp][kj]; kn = kn>1e-24f? kn:1e-24f;
  dt = dt/sqrtf(kn)*0.125f;
  if(sts[grp][qi]==sts[grp][kj]) dt=-5e4f;
  PR[((size_t)bh*2080 + c*4 + qi)*8 + kj] = dt;
  float mx=dt;
  for(int o=1;o<8;o<<=1){ float om=__shfl_xor(mx,o,64); mx=om>mx?om:mx; }
  float sm=expf(dt-mx);
  for(int o=1;o<8;o<<=1) sm+=__shfl_xor(sm,o,64);
  if(kj==0) lse[(size_t)bh*2080 + c*4 + qi] = mx + logf(sm);
}

// ---- dots -> probs (in-place in PR); per-token LSE over 4 rounds inlined ---
__global__ void k_probs(const float* __restrict__ lse, const unsigned short* __restrict__ sticker,
    const unsigned short* __restrict__ undo, float* __restrict__ PR){
  int j=blockIdx.x*256+threadIdx.x;     // BH*2080 slots
  if(j>=BH_*2080) return;
  int bh=j/2080;
  const unsigned short* u=undo+(size_t)bh*2080;
  const float* ls=lse+(size_t)bh*2080;
  float L=lse[j];
  int p=(int)sticker[j]%TPAD;
  float l0=ls[u[p]], l1=ls[u[TPAD+p]], l2=ls[u[2*TPAD+p]], l3=ls[u[3*TPAD+p]];
  float mx=fmaxf(fmaxf(l0,l1),fmaxf(l2,l3));
  float lt=mx+logf(expf(l0-mx)+expf(l1-mx)+expf(l2-mx)+expf(l3-mx));
  float w=expf(L-lt);
  float* pr=PR+(size_t)j*8;
  float4 d0=*(float4*)pr, d1=*(float4*)(pr+4);
  d0.x=expf(d0.x-L)*w; d0.y=expf(d0.y-L)*w; d0.z=expf(d0.z-L)*w; d0.w=expf(d0.w-L)*w;
  d1.x=expf(d1.x-L)*w; d1.y=expf(d1.y-L)*w; d1.z=expf(d1.z-L)*w; d1.w=expf(d1.w-L)*w;
  *(float4*)pr=d0; *(float4*)(pr+4)=d1;
}

// ------- attention gather: out[b,t,:] = sum P*v, split-write hi/lo ----------
__global__ __launch_bounds__(256) void k_gather(const float* __restrict__ v,
    const unsigned short* __restrict__ sticker, const unsigned short* __restrict__ undo,
    const float* __restrict__ PR, unsigned short* __restrict__ ahi,
    unsigned short* __restrict__ alo){
  __shared__ int   ridx[8][32];
  __shared__ float pval[8][32];
  int b=blockIdx.x, t=blockIdx.y;
  int tid=threadIdx.x, hd=tid>>5, l=tid&31;
  int bh=b*8+hd;
  const unsigned short* stk = sticker + (size_t)bh*2080;
  const unsigned short* ud  = undo    + (size_t)bh*2080;
  {
    int h=l>>3, kj=l&7;
    int j = (int)ud[h*TPAD+t];
    int c = j>>2;
    int slot = (kj<4)? (c*4+kj) : (((c+NCH_-1)%NCH_)*4 + (kj-4));
    ridx[hd][l] = (int)stk[slot]%TPAD;
    pval[hd][l] = PR[((size_t)bh*2080 + j)*8 + kj];
  }
  __syncthreads();
  int f0=l*2;
  float a0=0.f, a1=0.f;
  const float* vb = v + (size_t)b*TPAD*D_ + hd*64 + f0;
  for(int i=0;i<32;i++){
    const float* vr = vb + (size_t)ridx[hd][i]*D_;
    float p=pval[hd][i];
    a0 += p*vr[0];
    a1 += p*vr[1];
  }
  size_t off = ((size_t)b*NTOK + t)*(size_t)D_ + hd*64 + f0;
  unsigned short h0=f2bf(a0), h1=f2bf(a1);
  ahi[off]=h0; ahi[off+1]=h1;
  alo[off]=f2bf(a0-bf2f(h0)); alo[off+1]=f2bf(a1-bf2f(h1));
}

// -------- x = LN(x + delta)*g + b ; also split-write hi/lo ------------------
__global__ __launch_bounds__(256) void k_addln(float* __restrict__ x,
    const float* __restrict__ delta, const float* __restrict__ g,
    const float* __restrict__ bb, unsigned short* __restrict__ xhi,
    unsigned short* __restrict__ xlo){
  __shared__ float red[4];
  int row=blockIdx.x, tid=threadIdx.x;
  size_t base=(size_t)row*D_;
  float v0=x[base+tid]+delta[base+tid];
  float v1=x[base+tid+256]+delta[base+tid+256];
  float m=blockReduce256(v0+v1,red,tid)*(1.f/512.f);
  float d0=v0-m, d1=v1-m;
  float var=blockReduce256(d0*d0+d1*d1,red,tid)*(1.f/512.f);
  float inv=1.f/sqrtf(var+1e-5f);
  float y0=d0*inv*g[tid]    +bb[tid];
  float y1=d1*inv*g[tid+256]+bb[tid+256];
  x[base+tid]=y0; x[base+tid+256]=y1;
  unsigned short h0=f2bf(y0), h1=f2bf(y1);
  xhi[base+tid]=h0; xhi[base+tid+256]=h1;
  xlo[base+tid]=f2bf(y0-bf2f(h0)); xlo[base+tid+256]=f2bf(y1-bf2f(h1));
}

// ---------------- final LN on last token + projection -----------------------
__global__ __launch_bounds__(256) void k_dec(const float* __restrict__ x,
    const float* __restrict__ gF, const float* __restrict__ bF,
    const float* __restrict__ Wp, const float* __restrict__ bp,
    float* __restrict__ dec){
  __shared__ float red[4];
  int b=blockIdx.x, tid=threadIdx.x;
  const float* row = x + ((size_t)b*NTOK + (NTOK-1))*(size_t)D_;
  float v0=row[tid], v1=row[tid+256];
  float m=blockReduce256(v0+v1,red,tid)*(1.f/512.f);
  float d0=v0-m, d1=v1-m;
  float var=blockReduce256(d0*d0+d1*d1,red,tid)*(1.f/512.f);
  float inv=1.f/sqrtf(var+1e-5f);
  float y0=d0*inv*gF[tid]    +bF[tid];
  float y1=d1*inv*gF[tid+256]+bF[tid+256];
  float dd=blockReduce256(y0*Wp[tid]+y1*Wp[tid+256],red,tid);
  if(tid==0) dec[b]=dd+bp[0];
}

__global__ void k_out(const float* __restrict__ dec, const float* __restrict__ means,
    const float* __restrict__ stdev, float* __restrict__ out){
  int idx=blockIdx.x*256+threadIdx.x;
  int e=idx&511, j=(idx>>9)&31, i=idx>>14;
  out[idx]=dec[j]*stdev[i*E_+e]+means[i*E_+e];
}

// ============================================================================
extern "C" void kernel_launch(void* const* d_in, const int* in_sizes, int n_in,
                              void* d_out, int out_size, void* d_ws, size_t ws_size,
                              hipStream_t stream){
  (void)in_sizes; (void)n_in; (void)out_size;
  const float* xe   = (const float*)d_in[0];
  const float* xm   = (const float*)d_in[1];
  const float* Wemb = (const float*)d_in[2];
  const float* bemb = (const float*)d_in[3];
  const float* Wqk  = (const float*)d_in[4];
  const float* Wv   = (const float*)d_in[5];
  const float* Wo   = (const float*)d_in[6];
  const float* boP  = (const float*)d_in[7];
  const float* Wc1  = (const float*)d_in[8];
  const float* bc1  = (const float*)d_in[9];
  const float* Wc2  = (const float*)d_in[10];
  const float* bc2  = (const float*)d_in[11];
  const float* g1   = (const float*)d_in[12];
  const float* b1   = (const float*)d_in[13];
  const float* g2   = (const float*)d_in[14];
  const float* b2   = (const float*)d_in[15];
  const float* gF   = (const float*)d_in[16];
  const float* bF   = (const float*)d_in[17];
  const float* Wp   = (const float*)d_in[18];
  const float* bp   = (const float*)d_in[19];
  const float* rot  = (const float*)d_in[20];
  float* out = (float*)d_out;

  // ---- workspace carve ----
  char* w=(char*)d_ws;
  auto carve=[&](size_t n)->char*{ char* p=w; w += (n+255)&~(size_t)255; return p; };
  float* means=(float*)carve(65536);
  float* stdev=(float*)carve(65536);
  float* dec  =(float*)carve(256);
  unsigned short* zp=(unsigned short*)carve(512);              // zero page
  float* rT   =(float*)carve(166400);                          // 2 x [4][5][64][16] fp32
  float* x    =(float*)carve((size_t)B_*NTOK*D_*4);            // 33.8 MB
  unsigned short* xhi=(unsigned short*)carve((size_t)B_*NTOK*D_*2); // 16.9
  unsigned short* xlo=(unsigned short*)carve((size_t)B_*NTOK*D_*2); // 16.9
  float* BIG  =(float*)carve((size_t)B_*TPAD*D_*4);            // 34.1 (qk/v/delta)
  constexpr size_t WTOT=6029312;
  unsigned short* whi=(unsigned short*)carve(WTOT*2);          // 12.1
  unsigned short* wlo=(unsigned short*)carve(WTOT*2);          // 12.1
  // Union arena: [PR|bkt|stk|ud|lse] (attention) vs [hid] (FFN).
  constexpr size_t UBASE=45088768;
  constexpr size_t UFULL=(size_t)16512*2048*2;                 // 67.6 MB
  size_t used=(size_t)(w-(char*)d_ws);
  bool fullffn = ws_size >= used + UFULL + 4096;
  char* U = carve(fullffn ? UFULL : UBASE);
  float*          PR    =(float*)U;                                   // 17.04 MB
  unsigned char*  bkt   =(unsigned char*) (U+17039360);               // 0.53
  unsigned short* stk   =(unsigned short*)(U+17039360+532480);        // 1.06
  unsigned short* ud    =(unsigned short*)(U+17039360+532480+1064960);// 1.06
  float*          lseB  =(float*)(U+17039360+532480+2129920);         // 2.13
  unsigned short* hidHi =(unsigned short*)U;                          // 34.1 or 67.6 MB

  hipMemsetAsync(zp,0,512,stream);

  // weight arena offsets (elements); per-layer strides
  constexpr size_t oWemb=0, oWqk=262144, oWv=786432, oWo=1310720,
                   oWc1=1835008, oWc2=3932160;
  constexpr size_t Wsz=262144, C1sz=1048576, C2sz=1048576;

  // ---- split weights once (n = TOTAL elements) ----
  k_split<<<(262144+255)/256,256,0,stream>>>(Wemb,whi+oWemb,wlo+oWemb,262144);
  k_split<<<(524288+255)/256,256,0,stream>>>(Wqk, whi+oWqk, wlo+oWqk, 524288);
  k_split<<<(524288+255)/256,256,0,stream>>>(Wv,  whi+oWv,  wlo+oWv,  524288);
  k_split<<<(524288+255)/256,256,0,stream>>>(Wo,  whi+oWo,  wlo+oWo,  524288);
  k_split<<<(2097152+255)/256,256,0,stream>>>(Wc1, whi+oWc1, wlo+oWc1, 2097152);
  k_split<<<(2097152+255)/256,256,0,stream>>>(Wc2, whi+oWc2, wlo+oWc2, 2097152);
  k_rotTile<<<(2*16640+255)/256,256,0,stream>>>(rot,rT);   // both layers

  // ---- embedding: GEMM writes x (no alias), then split x -> xhi/xlo ----
  k_revin<<<dim3(2,B_),256,0,stream>>>(xe,means,stdev);
  k_pack_tok<<<dim3(8,8,B_),256,0,stream>>>(xe,means,stdev,xhi,xlo);
  k_pack_marks<<<(B_*NMARK_*L_)/256,256,0,stream>>>(xm,xhi,xlo);
  k_gemm<0,false,true><<<dim3(4,129),256,0,stream>>>(xhi,xlo,whi+oWemb,wlo+oWemb,bemb,x,nullptr,nullptr,zp,16512,512,512);
  k_split<<<(B_*NTOK*D_+255)/256,256,0,stream>>>(x,xhi,xlo,B_*NTOK*D_);

  for(int l=0;l<NLAYERS_;l++){
    const unsigned short* Wqk_h=whi+oWqk+(size_t)l*Wsz, *Wqk_l2=wlo+oWqk+(size_t)l*Wsz;
    const unsigned short* Wv_h =whi+oWv +(size_t)l*Wsz, *Wv_l2 =wlo+oWv +(size_t)l*Wsz;
    const unsigned short* Wo_h =whi+oWo +(size_t)l*Wsz, *Wo_l2 =wlo+oWo +(size_t)l*Wsz;
    const unsigned short* Wc1_h=whi+oWc1+(size_t)l*C1sz,*Wc1_l2=wlo+oWc1+(size_t)l*C1sz;
    const unsigned short* Wc2_h=whi+oWc2+(size_t)l*C2sz,*Wc2_l2=wlo+oWc2+(size_t)l*C2sz;
    const float* bo_l =boP+(size_t)l*D_;
    const float* bc1_l=bc1+(size_t)l*DFF_;
    const float* bc2_l=bc2+(size_t)l*D_;
    const float* g1_l=g1+(size_t)l*D_;
    const float* b1_l=b1+(size_t)l*D_;
    const float* g2_l=g2+(size_t)l*D_;
    const float* b2_l=b2+(size_t)l*D_;
    const float* rT_l=rT+(size_t)l*20800;

    // qk projection (FULL precision hi/lo, hybrid-buffered 48KB -> 1 round)
    k_gemm<0,true,true><<<dim3(4,130),256,0,stream>>>(xhi,xlo,Wqk_h,Wqk_l2,nullptr,BIG,nullptr,nullptr,zp,16640,512,512);
    // LSH routing + exact stable sort
    k_buckets<<<dim3(BH_,9),256,0,stream>>>(BIG,rT_l,bkt);
    k_sort<<<BH_,64,0,stream>>>(bkt,stk,ud);
    // LSE + dots (stored), then elementwise probs (wlse inlined)
    k_attn1<<<16640,256,0,stream>>>(BIG,stk,lseB,PR);
    k_probs<<<(BH_*2080+255)/256,256,0,stream>>>(lseB,stk,ud,PR);
    // v projection (A = xhi only: 2 MFMAs, dropped xlo@Wv ~2^-9 rel)
    k_gemm<0,true,false><<<dim3(4,130),256,0,stream>>>(xhi,zp,Wv_h,Wv_l2,nullptr,BIG,nullptr,nullptr,zp,16640,512,512);
    k_gather<<<dim3(B_,NTOK),256,0,stream>>>(BIG,stk,ud,PR,xhi,xlo);
    // output projection (A = attn-out hi only)
    k_gemm<0,false,false><<<dim3(4,129),256,0,stream>>>(xhi,zp,Wo_h,Wo_l2,bo_l,BIG,nullptr,nullptr,zp,16512,512,512);
    k_addln<<<16512,256,0,stream>>>(x,BIG,g1_l,b1_l,xhi,xlo);
    // FFN. Hidden = bf16 HI only (OUTMODE=3); c1/c2 AFULL=false (2 MFMAs).
    if(fullffn){
      k_gemm<3,false,false><<<dim3(16,129),256,0,stream>>>(xhi,zp,Wc1_h,Wc1_l2,bc1_l,nullptr,hidHi,nullptr,zp,16512,2048,512);
      k_gemm<0,false,false><<<dim3(4,129),256,0,stream>>>(hidHi,zp,Wc2_h,Wc2_l2,bc2_l,BIG,nullptr,nullptr,zp,16512,512,2048);
    } else {
      const int rows0[2]={0,8320}, mrows[2]={8320,8192}, rblk[2]={65,64};
      for(int ch=0; ch<2; ch++){
        size_t rs=(size_t)rows0[ch];
        k_gemm<3,false,false><<<dim3(16,rblk[ch]),256,0,stream>>>(xhi+rs*D_,zp,Wc1_h,Wc1_l2,bc1_l,nullptr,hidHi,nullptr,zp,mrows[ch],2048,512);
        k_gemm<0,false,false><<<dim3(4,rblk[ch]),256,0,stream>>>(hidHi,zp,Wc2_h,Wc2_l2,bc2_l,BIG+rs*D_,nullptr,nullptr,zp,mrows[ch],512,2048);
      }
    }
    k_addln<<<16512,256,0,stream>>>(x,BIG,g2_l,b2_l,xhi,xlo);
  }

  k_dec<<<B_,256,0,stream>>>(x,gF,bF,Wp,bp,dec);
  k_out<<<2048,256,0,stream>>>(dec,means,stdev,out);
}

// Round 13
// 1319.929 us; speedup vs baseline: 1.0313x; 1.0313x over previous
//
#include <hip/hip_runtime.h>
#include <stdint.h>

// ============================================================================
// Reformer/LSH iTransformer forward on MI355X (gfx950). ALL I/O FP32.
// R21 = R20 + both-sides LDS bank-conflict swizzle in k_gemm (rule #21):
//   stage: lane loads global seg (lane&3)^(rsub&3)  (LDS dest stays linear)
//   read : element offset kk ^ ((row&3)<<3)
// R20 counters: fragment reads were 8-way bank conflicts (lanes 0-15 read the
// same 16B column of 16 consecutive 64B rows, stride 16 banks) -> 6.34M
// conflict-cycles per c2 dispatch (~4 cyc per ds_read_b128). XOR over the 2
// slot bits spreads to 4 banks x 4-way (1.58x vs 2.94x, m136) -- the floor
// given gload_lds's contiguous-dest constraint. Same data, same MFMA order ->
// absmax must stay EXACTLY 0.01171875.
// R20 kept: XCD-chunked swizzle (FETCH 138->52MB on c2, mechanism-confirmed).
// History: R14 -192, R16 -103, R17 -61, R18 -26, R19 -36, R20 ~0 (52MB FETCH).
// ============================================================================

constexpr int B_=32, L_=512, E_=512, NMARK_=4, D_=512, DFF_=2048, NLAYERS_=2;
constexpr int NTOK=516, TPAD=520, DH_=64, NB_=130, NHASH_=4;
constexpr int BH_=256, NCH_=520;

typedef __attribute__((ext_vector_type(8))) short v8s;
typedef __attribute__((ext_vector_type(4))) float v4f;

typedef __attribute__((address_space(1))) const unsigned int gu32;
typedef __attribute__((address_space(3))) unsigned int lu32;
static __device__ __forceinline__ void gload_lds16(const void* g, void* l){
  __builtin_amdgcn_global_load_lds((gu32*)g, (lu32*)l, 16, 0, 0);
}

static __device__ __forceinline__ unsigned short f2bf(float f){
  union{float f; unsigned int u;} c; c.f=f;
  unsigned int u=c.u;
  return (unsigned short)((u + 0x7fffu + ((u>>16)&1u))>>16);  // RNE
}
static __device__ __forceinline__ float bf2f(unsigned short h){
  union{unsigned int u; float f;} c; c.u=((unsigned int)h)<<16; return c.f;
}
static __device__ __forceinline__ float blockReduce256(float v, float* red, int tid){
  for(int o=32;o;o>>=1) v += __shfl_down(v,o,64);
  __syncthreads();
  if((tid&63)==0) red[tid>>6]=v;
  __syncthreads();
  return red[0]+red[1]+red[2]+red[3];
}

// ---------------- generic fp32 -> (hi,lo) bf16 split ------------------------
__global__ void k_split(const float* __restrict__ src, unsigned short* __restrict__ hi,
    unsigned short* __restrict__ lo, int n){
  int idx=blockIdx.x*256+threadIdx.x;
  if(idx>=n) return;
  float v=src[idx];
  unsigned short h=f2bf(v);
  hi[idx]=h; lo[idx]=f2bf(v-bf2f(h));
}

// ---------------- RevIN stats over L per (b,e) ------------------------------
__global__ __launch_bounds__(256) void k_revin(const float* __restrict__ xe,
    float* __restrict__ means, float* __restrict__ stdev){
  int b=blockIdx.y;
  int e=blockIdx.x*256+threadIdx.x;
  const float* p = xe + (size_t)b*L_*E_ + e;
  float s=0.f,s2=0.f;
  for(int l=0;l<L_;l++){ float v=p[(size_t)l*E_]; s+=v; s2+=v*v; }
  float m=s*(1.f/512.f);
  float var=s2*(1.f/512.f)-m*m;
  var = var>0.f? var:0.f;
  means[b*E_+e]=m;
  stdev[b*E_+e]=sqrtf(var+1e-5f);
}

// ------- transpose x_enc -> token rows with RevIN, split-write hi/lo --------
__global__ __launch_bounds__(256) void k_pack_tok(const float* __restrict__ xe,
     const float* __restrict__ means, const float* __restrict__ stdev,
     unsigned short* __restrict__ hi, unsigned short* __restrict__ lo){
  __shared__ float tile[64][65];
  int b=blockIdx.z;
  int ct=blockIdx.x*64, lt=blockIdx.y*64;
  int tid=threadIdx.x;
  int i=tid>>2, j0=(tid&3)*16;
  {
    const float* src = xe + ((size_t)b*L_ + lt + i)*E_ + ct + j0;
    float tmp[16];
    *(float4*)&tmp[0]  = *(const float4*)(src);
    *(float4*)&tmp[4]  = *(const float4*)(src+4);
    *(float4*)&tmp[8]  = *(const float4*)(src+8);
    *(float4*)&tmp[12] = *(const float4*)(src+12);
    for(int j=0;j<16;j++) tile[i][j0+j]=tmp[j];
  }
  __syncthreads();
  {
    float ms=means[b*E_+ct+i];
    float sd=stdev[b*E_+ct+i];
    unsigned short hs[16], ls[16];
    for(int j=0;j<16;j++){
      float v=(tile[j0+j][i]-ms)/sd;
      unsigned short hh=f2bf(v);
      hs[j]=hh; ls[j]=f2bf(v-bf2f(hh));
    }
    size_t off = ((size_t)b*NTOK + ct + i)*(size_t)L_ + lt + j0;
    *(uint4*)&hi[off]   = *(uint4*)&hs[0];
    *(uint4*)&hi[off+8] = *(uint4*)&hs[8];
    *(uint4*)&lo[off]   = *(uint4*)&ls[0];
    *(uint4*)&lo[off+8] = *(uint4*)&ls[8];
  }
}

__global__ void k_pack_marks(const float* __restrict__ xm,
    unsigned short* __restrict__ hi, unsigned short* __restrict__ lo){
  int idx=blockIdx.x*256+threadIdx.x; // 32*4*512
  int l=idx&511, j=(idx>>9)&3, b=idx>>11;
  float v = xm[((size_t)b*L_ + l)*NMARK_ + j];
  unsigned short hh=f2bf(v);
  size_t off=((size_t)b*NTOK + E_ + j)*(size_t)L_ + l;
  hi[off]=hh; lo[off]=f2bf(v-bf2f(hh));
}

// ------ 128x128 bf16 MFMA GEMM, 48 KB LDS both variants -> 3 blk/CU ---------
// XCD-chunked block swizzle + both-sides LDS XOR bank swizzle.
// AFULL=true : hi tiles double-buffered, lo tiles single-buffered (2 barriers
//              per iter); 3 MFMAs. AFULL=false: 3 tiles double-buffered; 2.
// OUTMODE 0: fp32 C. 3: relu + bf16-hi only.
// TPADDED: M rows indexed b*520+t, A from compact [b*516+t], t>=516 -> zeropad.
template<int OUTMODE, bool TPADDED, bool AFULL>
__global__ __launch_bounds__(256) void k_gemm(
    const unsigned short* __restrict__ Ahi, const unsigned short* __restrict__ Alo,
    const unsigned short* __restrict__ Bhi, const unsigned short* __restrict__ Blo,
    const float* __restrict__ bias, float* __restrict__ Cf,
    unsigned short* __restrict__ Chi, unsigned short* __restrict__ Clo,
    const unsigned short* __restrict__ zeropad,
    int M, int N, int K)
{
  __shared__ __align__(16) unsigned short LDS[6][128*32];   // 48 KB
  // ---- XCD-chunked swizzle (bijective, any grid size; m204 form) ----
  int flat = blockIdx.y*gridDim.x + blockIdx.x;
  int ntot = gridDim.x*gridDim.y;
  int q = ntot>>3, r = ntot&7;
  int xcd = flat&7, jj = flat>>3;
  int f2 = xcd*q + (xcd<r?xcd:r) + jj;
  const int m0=(f2/(int)gridDim.x)*128, n0=(f2%(int)gridDim.x)*128;
  const int tid=threadIdx.x, lane=tid&63, wave=tid>>6;
  const int wm=(wave>>1)*64, wn=(wave&1)*64;

  // wave->tile: AFULL: 0=Ahi 1=Alo 2=Bhi 3=Blo ; else: 0=Ahi 1=Bhi 2=Blo.
  // Stage: call j covers rows j*16..j*16+15; lane i -> row j*16+(i>>2).
  // Bank swizzle: lane loads global 16B-slot ((i&3) ^ (row&3)) -- LDS dest
  // stays linear (gload_lds constraint); reads XOR the same bits back.
  const unsigned short* srcp;
  bool isA;
  if constexpr (AFULL){
    srcp = (wave==0)?Ahi:(wave==1)?Alo:(wave==2)?Bhi:Blo;
    isA  = (wave<2);
  } else {
    srcp = (wave==0)?Ahi:(wave==1)?Bhi:Blo;   // wave 3 idles
    isA  = (wave==0);
  }
  const bool stager = AFULL || (wave<3);
  const int rsub=lane>>2, seg=(((lane&3)^(rsub&3)))*8;   // source permute
  const unsigned short* gp[8]; int stp[8];
  #pragma unroll
  for(int j=0;j<8;j++){
    int row=j*16+rsub;
    if(isA){
      size_t ao; bool valid=true;
      int g=m0+row;
      if constexpr (TPADDED){
        int b=g/TPAD; int t=g-b*TPAD; valid=(t<NTOK);
        ao=((size_t)b*NTOK + (valid?t:0))*(size_t)K;
      } else ao=(size_t)g*(size_t)K;
      gp[j]= valid ? (srcp+ao+seg) : (zeropad+seg);
      stp[j]= valid ? 32 : 0;
    } else {
      gp[j]= srcp + (size_t)(n0+row)*(size_t)K + seg;
      stp[j]=32;
    }
  }

  v4f acc[4][4];
  for(int i=0;i<4;i++)for(int j=0;j<4;j++) acc[i][j]=(v4f){0.f,0.f,0.f,0.f};
  const int am = wm + (lane&15);
  const int bn = wn + (lane&15);
  const int kk = (lane>>4)*8;
  const int ka = kk ^ ((am&3)<<3);   // read-side XOR (A rows)
  const int kb = kk ^ ((bn&3)<<3);   // read-side XOR (B rows)
  const int nIter=K/32;

  if constexpr (AFULL){
    // prologue: wave0->Ahi buf0 (LDS0), wave2->Bhi buf0 (LDS1),
    //           wave1->Alo (LDS4), wave3->Blo (LDS5)
    {
      unsigned short* dst0 = (wave==0)?&LDS[0][0]:(wave==2)?&LDS[1][0]
                            :(wave==1)?&LDS[4][0]:&LDS[5][0];
      #pragma unroll
      for(int j=0;j<8;j++){ gload_lds16(gp[j], dst0+j*512); gp[j]+=stp[j]; }
    }
    for(int k=0;k<nIter;k++){
      __syncthreads();   // drains: hi buf[k&1] + lo(k) complete
      if(k+1<nIter && (wave==0||wave==2)){   // hi prefetch overlaps MFMAs
        unsigned short* nxt=&LDS[((k+1)&1)*2+(wave>>1)][0];
        #pragma unroll
        for(int j=0;j<8;j++){ gload_lds16(gp[j], nxt+j*512); gp[j]+=stp[j]; }
      }
      const unsigned short* curA =&LDS[(k&1)*2+0][0];
      const unsigned short* curB =&LDS[(k&1)*2+1][0];
      const unsigned short* curAl=&LDS[4][0];
      const unsigned short* curBl=&LDS[5][0];
      v8s a[4], al[4], b[4], bl[4];
      for(int t=0;t<4;t++){
        a[t] =*(const v8s*)&curA [(am+t*16)*32+ka];
        al[t]=*(const v8s*)&curAl[(am+t*16)*32+ka];
        b[t] =*(const v8s*)&curB [(bn+t*16)*32+kb];
        bl[t]=*(const v8s*)&curBl[(bn+t*16)*32+kb];
      }
      for(int mt=0;mt<4;mt++)for(int nt=0;nt<4;nt++){
        acc[mt][nt]=__builtin_amdgcn_mfma_f32_16x16x32_bf16(al[mt],b[nt], acc[mt][nt],0,0,0);
        acc[mt][nt]=__builtin_amdgcn_mfma_f32_16x16x32_bf16(a[mt], bl[nt],acc[mt][nt],0,0,0);
        acc[mt][nt]=__builtin_amdgcn_mfma_f32_16x16x32_bf16(a[mt], b[nt], acc[mt][nt],0,0,0);
      }
      if(k+1<nIter){     // k uniform -> barrier uniform
        __syncthreads(); // all waves done READING lo(k)
        if(wave==1||wave==3){   // re-stage lo(k+1) into the single buffer
          unsigned short* nxt=&LDS[4+(wave>>1)][0];
          #pragma unroll
          for(int j=0;j<8;j++){ gload_lds16(gp[j], nxt+j*512); gp[j]+=stp[j]; }
        }
      }
    }
  } else {
    // prologue: DMA tile 0 into buf 0 (tiles = LDS[buf*3 + {0,1,2}])
    if(stager){
      #pragma unroll
      for(int j=0;j<8;j++){ gload_lds16(gp[j], &LDS[wave][j*512]); gp[j]+=stp[j]; }
    }
    for(int k=0;k<nIter;k++){
      __syncthreads();   // buf[k&1] DMA complete
      if(k+1<nIter && stager){
        unsigned short* nxt=&LDS[((k+1)&1)*3+wave][0];
        #pragma unroll
        for(int j=0;j<8;j++){ gload_lds16(gp[j], nxt+j*512); gp[j]+=stp[j]; }
      }
      const unsigned short* curA =&LDS[(k&1)*3+0][0];
      const unsigned short* curB =&LDS[(k&1)*3+1][0];
      const unsigned short* curBl=&LDS[(k&1)*3+2][0];
      v8s a[4], b[4], bl[4];
      for(int t=0;t<4;t++){
        a[t] =*(const v8s*)&curA [(am+t*16)*32+ka];
        b[t] =*(const v8s*)&curB [(bn+t*16)*32+kb];
        bl[t]=*(const v8s*)&curBl[(bn+t*16)*32+kb];
      }
      for(int mt=0;mt<4;mt++)for(int nt=0;nt<4;nt++){
        acc[mt][nt]=__builtin_amdgcn_mfma_f32_16x16x32_bf16(a[mt], bl[nt],acc[mt][nt],0,0,0);
        acc[mt][nt]=__builtin_amdgcn_mfma_f32_16x16x32_bf16(a[mt], b[nt], acc[mt][nt],0,0,0);
      }
    }
  }
  // C/D mapping: col=lane&15, row=(lane>>4)*4+r
  for(int mt=0;mt<4;mt++)for(int nt=0;nt<4;nt++){
    int col = n0 + wn + nt*16 + (lane&15);
    int rb  = m0 + wm + mt*16 + (lane>>4)*4;
    float bv = bias ? bias[col] : 0.f;
    for(int r2=0;r2<4;r2++){
      float v = acc[mt][nt][r2] + bv;
      size_t off=(size_t)(rb+r2)*N + col;
      if constexpr (OUTMODE==0){
        Cf[off]=v;
      } else {                            // OUTMODE==3: relu + hi-only bf16
        v = v>0.f ? v : 0.f;
        Chi[off]=f2bf(v);
      }
    }
  }
  (void)Clo;
}

// --- rot[f][h][i] (64 x 4 x 65) -> rT[h][tile][f][16] (i = tile*13+j, j<13) -
__global__ void k_rotTile(const float* __restrict__ rot, float* __restrict__ rT){
  int idx=blockIdx.x*256+threadIdx.x;   // 2 layers x 16640
  if(idx>=2*64*260) return;
  int lyr=idx/16640, r2=idx-lyr*16640;
  int f=r2/260, r=r2-f*260;             // r = h*65+i
  int h=r/65, i=r-h*65;
  int tile=i/13, j=i-tile*13;
  rT[(size_t)lyr*20800 + (((size_t)(h*5+tile)*64)+f)*16 + j]=rot[idx];
}

// ---------------- LSH buckets: wave=hash, thread=token, 5x13 output tiles ---
// (R13 version, best measured: 89us, VGPR 20, no spill.)
__global__ __launch_bounds__(256) void k_buckets(const float* __restrict__ qk,
    const float* __restrict__ rT, unsigned char* __restrict__ buckets){
  __shared__ float qkT[64*69];   // [f][t], stride 69 -> conflict-free
  int bh=blockIdx.x, tc=blockIdx.y;
  int b=bh>>3, hd=bh&7;
  int t0=tc*64;
  int tid=threadIdx.x;
  for(int j=tid;j<4096;j+=256){
    int t=j>>6, f=j&63;
    int tg=t0+t;
    qkT[f*69+t] = (tg<TPAD)? qk[((size_t)b*TPAD+tg)*(size_t)D_ + hd*64 + f] : 0.f;
  }
  __syncthreads();
  int h = __builtin_amdgcn_readfirstlane(tid>>6);   // wave-uniform hash
  int t = tid&63;
  float bv=-1.f; int bi=0x7fffffff;                 // cv >= 0 always
  #pragma unroll 1
  for(int tile=0; tile<5; ++tile){
    const float* rr = rT + ((size_t)(h*5+tile)*64)*16;  // wave-uniform
    float acc[13];
    #pragma unroll
    for(int j=0;j<13;j++) acc[j]=0.f;
    #pragma unroll 2
    for(int f=0;f<64;f++){
      float q = qkT[f*69+t];
      const float* rf = rr + f*16;
      #pragma unroll
      for(int j=0;j<13;j++) acc[j] += q*rf[j];
    }
    #pragma unroll
    for(int j=0;j<13;j++){
      int i = tile*13+j;
      float r=acc[j]; float cv; int ci;
      if(r>=-r){cv=r;ci=i;}else{cv=-r;ci=i+65;}
      if(cv>bv||(cv==bv&&ci<bi)){bv=cv;bi=ci;}
    }
  }
  int tg=t0+t;
  if(tg<TPAD) buckets[((size_t)bh*4+h)*TPAD+tg]=(unsigned char)bi;
}

// ---------------- stable counting sort == jnp.argsort(bucket*t+pos) ---------
__global__ __launch_bounds__(64) void k_sort(const unsigned char* __restrict__ buckets,
    unsigned short* __restrict__ sticker, unsigned short* __restrict__ undo){
  __shared__ int cnt[520];
  __shared__ int offs[520];
  int bh=blockIdx.x, tid=threadIdx.x;
  const unsigned char* bb = buckets + (size_t)bh*4*TPAD;
  for(int i=tid;i<520;i+=64) cnt[i]=0;
  __syncthreads();
  for(int i=tid;i<2080;i+=64){
    int h=i/TPAD;
    atomicAdd(&cnt[(int)bb[i]+h*NB_],1);
  }
  __syncthreads();
  if(tid==0){ int s=0; for(int k2=0;k2<520;k2++){ offs[k2]=s; s+=cnt[k2]; } }
  __syncthreads();
  if(tid<4){
    int h=tid;
    unsigned short* stk = sticker + (size_t)bh*2080;
    unsigned short* ud  = undo    + (size_t)bh*2080;
    for(int p=0;p<TPAD;p++){
      int key = (int)bb[h*TPAD+p] + h*NB_;
      int j = offs[key]++;
      stk[j] = (unsigned short)(h*TPAD+p);
      ud[h*TPAD+p] = (unsigned short)j;
    }
  }
}

// -------- attention pass 1: per-chunk LSE + store masked dots into PR -------
__global__ __launch_bounds__(256) void k_attn1(const float* __restrict__ qk,
    const unsigned short* __restrict__ sticker, float* __restrict__ lse,
    float* __restrict__ PR){
  __shared__ float rows[8][8][68];
  __shared__ int   sts[8][8];
  __shared__ float n2s[8][8];
  int tid=threadIdx.x, grp=tid>>5, lane=tid&31;
  int gid=blockIdx.x*8+grp;
  int bh=gid/NCH_, c=gid-bh*NCH_;
  int b=bh>>3, hd=bh&7;
  const unsigned short* stk = sticker + (size_t)bh*2080;
  if(lane<8){
    int r=lane;
    int cprev=(c+NCH_-1)%NCH_;
    int j=(r<4)? c*4+r : cprev*4+(r-4);
    sts[grp][r]=(int)stk[j]%TPAD;
  }
  __syncthreads();
  #pragma unroll
  for(int it=0; it<2; it++){
    int j=lane+32*it;
    int r=j>>3, f0=(j&7)*8;
    const float* src=qk+((size_t)b*TPAD+sts[grp][r])*(size_t)D_+hd*64+f0;
    *(float4*)&rows[grp][r][f0]   = *(const float4*)src;
    *(float4*)&rows[grp][r][f0+4] = *(const float4*)(src+4);
  }
  __syncthreads();
  {
    int r=lane>>2, part=lane&3;
    float s=0.f;
    #pragma unroll
    for(int f=part*16; f<part*16+16; f++){ float v=rows[grp][r][f]; s+=v*v; }
    s+=__shfl_xor(s,1,64); s+=__shfl_xor(s,2,64);
    if(part==0) n2s[grp][r]=s;
  }
  __syncthreads();
  int qi=lane>>3, kj=lane&7;
  float dt=0.f;
  #pragma unroll
  for(int f=0;f<64;f++) dt += rows[grp][qi][f]*rows[grp][kj][f];
  float kn=n2s[grp][kj]; kn = kn>1e-24f? kn:1e-24f;
  dt = dt/sqrtf(kn)*0.125f;
  if(sts[grp][qi]==sts[grp][kj]) dt=-5e4f;
  PR[((size_t)bh*2080 + c*4 + qi)*8 + kj] = dt;
  float mx=dt;
  for(int o=1;o<8;o<<=1){ float om=__shfl_xor(mx,o,64); mx=om>mx?om:mx; }
  float sm=expf(dt-mx);
  for(int o=1;o<8;o<<=1) sm+=__shfl_xor(sm,o,64);
  if(kj==0) lse[(size_t)bh*2080 + c*4 + qi] = mx + logf(sm);
}

// ---- dots -> probs (in-place in PR); per-token LSE over 4 rounds inlined ---
__global__ void k_probs(const float* __restrict__ lse, const unsigned short* __restrict__ sticker,
    const unsigned short* __restrict__ undo, float* __restrict__ PR){
  int j=blockIdx.x*256+threadIdx.x;     // BH*2080 slots
  if(j>=BH_*2080) return;
  int bh=j/2080;
  const unsigned short* u=undo+(size_t)bh*2080;
  const float* ls=lse+(size_t)bh*2080;
  float L=lse[j];
  int p=(int)sticker[j]%TPAD;
  float l0=ls[u[p]], l1=ls[u[TPAD+p]], l2=ls[u[2*TPAD+p]], l3=ls[u[3*TPAD+p]];
  float mx=fmaxf(fmaxf(l0,l1),fmaxf(l2,l3));
  float lt=mx+logf(expf(l0-mx)+expf(l1-mx)+expf(l2-mx)+expf(l3-mx));
  float w=expf(L-lt);
  float* pr=PR+(size_t)j*8;
  float4 d0=*(float4*)pr, d1=*(float4*)(pr+4);
  d0.x=expf(d0.x-L)*w; d0.y=expf(d0.y-L)*w; d0.z=expf(d0.z-L)*w; d0.w=expf(d0.w-L)*w;
  d1.x=expf(d1.x-L)*w; d1.y=expf(d1.y-L)*w; d1.z=expf(d1.z-L)*w; d1.w=expf(d1.w-L)*w;
  *(float4*)pr=d0; *(float4*)(pr+4)=d1;
}

// ------- attention gather: out[b,t,:] = sum P*v, split-write hi/lo ----------
__global__ __launch_bounds__(256) void k_gather(const float* __restrict__ v,
    const unsigned short* __restrict__ sticker, const unsigned short* __restrict__ undo,
    const float* __restrict__ PR, unsigned short* __restrict__ ahi,
    unsigned short* __restrict__ alo){
  __shared__ int   ridx[8][32];
  __shared__ float pval[8][32];
  int b=blockIdx.x, t=blockIdx.y;
  int tid=threadIdx.x, hd=tid>>5, l=tid&31;
  int bh=b*8+hd;
  const unsigned short* stk = sticker + (size_t)bh*2080;
  const unsigned short* ud  = undo    + (size_t)bh*2080;
  {
    int h=l>>3, kj=l&7;
    int j = (int)ud[h*TPAD+t];
    int c = j>>2;
    int slot = (kj<4)? (c*4+kj) : (((c+NCH_-1)%NCH_)*4 + (kj-4));
    ridx[hd][l] = (int)stk[slot]%TPAD;
    pval[hd][l] = PR[((size_t)bh*2080 + j)*8 + kj];
  }
  __syncthreads();
  int f0=l*2;
  float a0=0.f, a1=0.f;
  const float* vb = v + (size_t)b*TPAD*D_ + hd*64 + f0;
  for(int i=0;i<32;i++){
    const float* vr = vb + (size_t)ridx[hd][i]*D_;
    float p=pval[hd][i];
    a0 += p*vr[0];
    a1 += p*vr[1];
  }
  size_t off = ((size_t)b*NTOK + t)*(size_t)D_ + hd*64 + f0;
  unsigned short h0=f2bf(a0), h1=f2bf(a1);
  ahi[off]=h0; ahi[off+1]=h1;
  alo[off]=f2bf(a0-bf2f(h0)); alo[off+1]=f2bf(a1-bf2f(h1));
}

// -------- x = LN(x + delta)*g + b ; also split-write hi/lo ------------------
__global__ __launch_bounds__(256) void k_addln(float* __restrict__ x,
    const float* __restrict__ delta, const float* __restrict__ g,
    const float* __restrict__ bb, unsigned short* __restrict__ xhi,
    unsigned short* __restrict__ xlo){
  __shared__ float red[4];
  int row=blockIdx.x, tid=threadIdx.x;
  size_t base=(size_t)row*D_;
  float v0=x[base+tid]+delta[base+tid];
  float v1=x[base+tid+256]+delta[base+tid+256];
  float m=blockReduce256(v0+v1,red,tid)*(1.f/512.f);
  float d0=v0-m, d1=v1-m;
  float var=blockReduce256(d0*d0+d1*d1,red,tid)*(1.f/512.f);
  float inv=1.f/sqrtf(var+1e-5f);
  float y0=d0*inv*g[tid]    +bb[tid];
  float y1=d1*inv*g[tid+256]+bb[tid+256];
  x[base+tid]=y0; x[base+tid+256]=y1;
  unsigned short h0=f2bf(y0), h1=f2bf(y1);
  xhi[base+tid]=h0; xhi[base+tid+256]=h1;
  xlo[base+tid]=f2bf(y0-bf2f(h0)); xlo[base+tid+256]=f2bf(y1-bf2f(h1));
}

// ---------------- final LN on last token + projection -----------------------
__global__ __launch_bounds__(256) void k_dec(const float* __restrict__ x,
    const float* __restrict__ gF, const float* __restrict__ bF,
    const float* __restrict__ Wp, const float* __restrict__ bp,
    float* __restrict__ dec){
  __shared__ float red[4];
  int b=blockIdx.x, tid=threadIdx.x;
  const float* row = x + ((size_t)b*NTOK + (NTOK-1))*(size_t)D_;
  float v0=row[tid], v1=row[tid+256];
  float m=blockReduce256(v0+v1,red,tid)*(1.f/512.f);
  float d0=v0-m, d1=v1-m;
  float var=blockReduce256(d0*d0+d1*d1,red,tid)*(1.f/512.f);
  float inv=1.f/sqrtf(var+1e-5f);
  float y0=d0*inv*gF[tid]    +bF[tid];
  float y1=d1*inv*gF[tid+256]+bF[tid+256];
  float dd=blockReduce256(y0*Wp[tid]+y1*Wp[tid+256],red,tid);
  if(tid==0) dec[b]=dd+bp[0];
}

__global__ void k_out(const float* __restrict__ dec, const float* __restrict__ means,
    const float* __restrict__ stdev, float* __restrict__ out){
  int idx=blockIdx.x*256+threadIdx.x;
  int e=idx&511, j=(idx>>9)&31, i=idx>>14;
  out[idx]=dec[j]*stdev[i*E_+e]+means[i*E_+e];
}

// ============================================================================
extern "C" void kernel_launch(void* const* d_in, const int* in_sizes, int n_in,
                              void* d_out, int out_size, void* d_ws, size_t ws_size,
                              hipStream_t stream){
  (void)in_sizes; (void)n_in; (void)out_size;
  const float* xe   = (const float*)d_in[0];
  const float* xm   = (const float*)d_in[1];
  const float* Wemb = (const float*)d_in[2];
  const float* bemb = (const float*)d_in[3];
  const float* Wqk  = (const float*)d_in[4];
  const float* Wv   = (const float*)d_in[5];
  const float* Wo   = (const float*)d_in[6];
  const float* boP  = (const float*)d_in[7];
  const float* Wc1  = (const float*)d_in[8];
  const float* bc1  = (const float*)d_in[9];
  const float* Wc2  = (const float*)d_in[10];
  const float* bc2  = (const float*)d_in[11];
  const float* g1   = (const float*)d_in[12];
  const float* b1   = (const float*)d_in[13];
  const float* g2   = (const float*)d_in[14];
  const float* b2   = (const float*)d_in[15];
  const float* gF   = (const float*)d_in[16];
  const float* bF   = (const float*)d_in[17];
  const float* Wp   = (const float*)d_in[18];
  const float* bp   = (const float*)d_in[19];
  const float* rot  = (const float*)d_in[20];
  float* out = (float*)d_out;

  // ---- workspace carve ----
  char* w=(char*)d_ws;
  auto carve=[&](size_t n)->char*{ char* p=w; w += (n+255)&~(size_t)255; return p; };
  float* means=(float*)carve(65536);
  float* stdev=(float*)carve(65536);
  float* dec  =(float*)carve(256);
  unsigned short* zp=(unsigned short*)carve(512);              // zero page
  float* rT   =(float*)carve(166400);                          // 2 x [4][5][64][16] fp32
  float* x    =(float*)carve((size_t)B_*NTOK*D_*4);            // 33.8 MB
  unsigned short* xhi=(unsigned short*)carve((size_t)B_*NTOK*D_*2); // 16.9
  unsigned short* xlo=(unsigned short*)carve((size_t)B_*NTOK*D_*2); // 16.9
  float* BIG  =(float*)carve((size_t)B_*TPAD*D_*4);            // 34.1 (qk/v/delta)
  constexpr size_t WTOT=6029312;
  unsigned short* whi=(unsigned short*)carve(WTOT*2);          // 12.1
  unsigned short* wlo=(unsigned short*)carve(WTOT*2);          // 12.1
  // Union arena: [PR|bkt|stk|ud|lse] (attention) vs [hid] (FFN).
  constexpr size_t UBASE=45088768;
  constexpr size_t UFULL=(size_t)16512*2048*2;                 // 67.6 MB
  size_t used=(size_t)(w-(char*)d_ws);
  bool fullffn = ws_size >= used + UFULL + 4096;
  char* U = carve(fullffn ? UFULL : UBASE);
  float*          PR    =(float*)U;                                   // 17.04 MB
  unsigned char*  bkt   =(unsigned char*) (U+17039360);               // 0.53
  unsigned short* stk   =(unsigned short*)(U+17039360+532480);        // 1.06
  unsigned short* ud    =(unsigned short*)(U+17039360+532480+1064960);// 1.06
  float*          lseB  =(float*)(U+17039360+532480+2129920);         // 2.13
  unsigned short* hidHi =(unsigned short*)U;                          // 34.1 or 67.6 MB

  hipMemsetAsync(zp,0,512,stream);

  // weight arena offsets (elements); per-layer strides
  constexpr size_t oWemb=0, oWqk=262144, oWv=786432, oWo=1310720,
                   oWc1=1835008, oWc2=3932160;
  constexpr size_t Wsz=262144, C1sz=1048576, C2sz=1048576;

  // ---- split weights once (n = TOTAL elements) ----
  k_split<<<(262144+255)/256,256,0,stream>>>(Wemb,whi+oWemb,wlo+oWemb,262144);
  k_split<<<(524288+255)/256,256,0,stream>>>(Wqk, whi+oWqk, wlo+oWqk, 524288);
  k_split<<<(524288+255)/256,256,0,stream>>>(Wv,  whi+oWv,  wlo+oWv,  524288);
  k_split<<<(524288+255)/256,256,0,stream>>>(Wo,  whi+oWo,  wlo+oWo,  524288);
  k_split<<<(2097152+255)/256,256,0,stream>>>(Wc1, whi+oWc1, wlo+oWc1, 2097152);
  k_split<<<(2097152+255)/256,256,0,stream>>>(Wc2, whi+oWc2, wlo+oWc2, 2097152);
  k_rotTile<<<(2*16640+255)/256,256,0,stream>>>(rot,rT);   // both layers

  // ---- embedding: GEMM writes x (no alias), then split x -> xhi/xlo ----
  k_revin<<<dim3(2,B_),256,0,stream>>>(xe,means,stdev);
  k_pack_tok<<<dim3(8,8,B_),256,0,stream>>>(xe,means,stdev,xhi,xlo);
  k_pack_marks<<<(B_*NMARK_*L_)/256,256,0,stream>>>(xm,xhi,xlo);
  k_gemm<0,false,true><<<dim3(4,129),256,0,stream>>>(xhi,xlo,whi+oWemb,wlo+oWemb,bemb,x,nullptr,nullptr,zp,16512,512,512);
  k_split<<<(B_*NTOK*D_+255)/256,256,0,stream>>>(x,xhi,xlo,B_*NTOK*D_);

  for(int l=0;l<NLAYERS_;l++){
    const unsigned short* Wqk_h=whi+oWqk+(size_t)l*Wsz, *Wqk_l2=wlo+oWqk+(size_t)l*Wsz;
    const unsigned short* Wv_h =whi+oWv +(size_t)l*Wsz, *Wv_l2 =wlo+oWv +(size_t)l*Wsz;
    const unsigned short* Wo_h =whi+oWo +(size_t)l*Wsz, *Wo_l2 =wlo+oWo +(size_t)l*Wsz;
    const unsigned short* Wc1_h=whi+oWc1+(size_t)l*C1sz,*Wc1_l2=wlo+oWc1+(size_t)l*C1sz;
    const unsigned short* Wc2_h=whi+oWc2+(size_t)l*C2sz,*Wc2_l2=wlo+oWc2+(size_t)l*C2sz;
    const float* bo_l =boP+(size_t)l*D_;
    const float* bc1_l=bc1+(size_t)l*DFF_;
    const float* bc2_l=bc2+(size_t)l*D_;
    const float* g1_l=g1+(size_t)l*D_;
    const float* b1_l=b1+(size_t)l*D_;
    const float* g2_l=g2+(size_t)l*D_;
    const float* b2_l=b2+(size_t)l*D_;
    const float* rT_l=rT+(size_t)l*20800;

    // qk projection (FULL precision hi/lo, hybrid-buffered 48KB -> 1 round)
    k_gemm<0,true,true><<<dim3(4,130),256,0,stream>>>(xhi,xlo,Wqk_h,Wqk_l2,nullptr,BIG,nullptr,nullptr,zp,16640,512,512);
    // LSH routing + exact stable sort
    k_buckets<<<dim3(BH_,9),256,0,stream>>>(BIG,rT_l,bkt);
    k_sort<<<BH_,64,0,stream>>>(bkt,stk,ud);
    // LSE + dots (stored), then elementwise probs (wlse inlined)
    k_attn1<<<16640,256,0,stream>>>(BIG,stk,lseB,PR);
    k_probs<<<(BH_*2080+255)/256,256,0,stream>>>(lseB,stk,ud,PR);
    // v projection (A = xhi only: 2 MFMAs, dropped xlo@Wv ~2^-9 rel)
    k_gemm<0,true,false><<<dim3(4,130),256,0,stream>>>(xhi,zp,Wv_h,Wv_l2,nullptr,BIG,nullptr,nullptr,zp,16640,512,512);
    k_gather<<<dim3(B_,NTOK),256,0,stream>>>(BIG,stk,ud,PR,xhi,xlo);
    // output projection (A = attn-out hi only)
    k_gemm<0,false,false><<<dim3(4,129),256,0,stream>>>(xhi,zp,Wo_h,Wo_l2,bo_l,BIG,nullptr,nullptr,zp,16512,512,512);
    k_addln<<<16512,256,0,stream>>>(x,BIG,g1_l,b1_l,xhi,xlo);
    // FFN. Hidden = bf16 HI only (OUTMODE=3); c1/c2 AFULL=false (2 MFMAs).
    if(fullffn){
      k_gemm<3,false,false><<<dim3(16,129),256,0,stream>>>(xhi,zp,Wc1_h,Wc1_l2,bc1_l,nullptr,hidHi,nullptr,zp,16512,2048,512);
      k_gemm<0,false,false><<<dim3(4,129),256,0,stream>>>(hidHi,zp,Wc2_h,Wc2_l2,bc2_l,BIG,nullptr,nullptr,zp,16512,512,2048);
    } else {
      const int rows0[2]={0,8320}, mrows[2]={8320,8192}, rblk[2]={65,64};
      for(int ch=0; ch<2; ch++){
        size_t rs=(size_t)rows0[ch];
        k_gemm<3,false,false><<<dim3(16,rblk[ch]),256,0,stream>>>(xhi+rs*D_,zp,Wc1_h,Wc1_l2,bc1_l,nullptr,hidHi,nullptr,zp,mrows[ch],2048,512);
        k_gemm<0,false,false><<<dim3(4,rblk[ch]),256,0,stream>>>(hidHi,zp,Wc2_h,Wc2_l2,bc2_l,BIG+rs*D_,nullptr,nullptr,zp,mrows[ch],512,2048);
      }
    }
    k_addln<<<16512,256,0,stream>>>(x,BIG,g2_l,b2_l,xhi,xlo);
  }

  k_dec<<<B_,256,0,stream>>>(x,gF,bF,Wp,bp,dec);
  k_out<<<2048,256,0,stream>>>(dec,means,stdev,out);
}

// Round 14
// 1247.000 us; speedup vs baseline: 1.0916x; 1.0585x over previous
//
#include <hip/hip_runtime.h>
#include <stdint.h>

// ============================================================================
// Reformer/LSH iTransformer forward on MI355X (gfx950). ALL I/O FP32.
// R22 = R21 + BFULL template flag; c2 runs AFULL=false,BFULL=false:
//  - drops Wc2-lo (error ~|y|*2^-9 ~ 8e-4 pre-LN, same scale as R14/R16 drops)
//  - 2 LDS tiles (Ahi,Bhi) dbuf = 32KB -> 5 blk/CU; 1 MFMA/pair; 8 reads/iter.
// R21 lesson: c2's SQ_LDS_BANK_CONFLICT = 792576 staging instrs x 8 cyc =
// pure DMA-write serialization; c2 is LDS-BANDWIDTH-bound (~280 LDS cyc vs
// ~154 MFMA cyc per iter). BFULL=false halves both traffic and MFMA work.
// History: R14 -192 (0.0117), R16 -103 (0.0156), R17 -61 (0.0117),
//          R18 -26, R19 -36, R20 ~0 (FETCH 138->52MB), R21 -41 (read swz).
// ============================================================================

constexpr int B_=32, L_=512, E_=512, NMARK_=4, D_=512, DFF_=2048, NLAYERS_=2;
constexpr int NTOK=516, TPAD=520, DH_=64, NB_=130, NHASH_=4;
constexpr int BH_=256, NCH_=520;

typedef __attribute__((ext_vector_type(8))) short v8s;
typedef __attribute__((ext_vector_type(4))) float v4f;

typedef __attribute__((address_space(1))) const unsigned int gu32;
typedef __attribute__((address_space(3))) unsigned int lu32;
static __device__ __forceinline__ void gload_lds16(const void* g, void* l){
  __builtin_amdgcn_global_load_lds((gu32*)g, (lu32*)l, 16, 0, 0);
}

static __device__ __forceinline__ unsigned short f2bf(float f){
  union{float f; unsigned int u;} c; c.f=f;
  unsigned int u=c.u;
  return (unsigned short)((u + 0x7fffu + ((u>>16)&1u))>>16);  // RNE
}
static __device__ __forceinline__ float bf2f(unsigned short h){
  union{unsigned int u; float f;} c; c.u=((unsigned int)h)<<16; return c.f;
}
static __device__ __forceinline__ float blockReduce256(float v, float* red, int tid){
  for(int o=32;o;o>>=1) v += __shfl_down(v,o,64);
  __syncthreads();
  if((tid&63)==0) red[tid>>6]=v;
  __syncthreads();
  return red[0]+red[1]+red[2]+red[3];
}

// ---------------- generic fp32 -> (hi,lo) bf16 split ------------------------
__global__ void k_split(const float* __restrict__ src, unsigned short* __restrict__ hi,
    unsigned short* __restrict__ lo, int n){
  int idx=blockIdx.x*256+threadIdx.x;
  if(idx>=n) return;
  float v=src[idx];
  unsigned short h=f2bf(v);
  hi[idx]=h; lo[idx]=f2bf(v-bf2f(h));
}

// ---------------- RevIN stats over L per (b,e) ------------------------------
__global__ __launch_bounds__(256) void k_revin(const float* __restrict__ xe,
    float* __restrict__ means, float* __restrict__ stdev){
  int b=blockIdx.y;
  int e=blockIdx.x*256+threadIdx.x;
  const float* p = xe + (size_t)b*L_*E_ + e;
  float s=0.f,s2=0.f;
  for(int l=0;l<L_;l++){ float v=p[(size_t)l*E_]; s+=v; s2+=v*v; }
  float m=s*(1.f/512.f);
  float var=s2*(1.f/512.f)-m*m;
  var = var>0.f? var:0.f;
  means[b*E_+e]=m;
  stdev[b*E_+e]=sqrtf(var+1e-5f);
}

// ------- transpose x_enc -> token rows with RevIN, split-write hi/lo --------
__global__ __launch_bounds__(256) void k_pack_tok(const float* __restrict__ xe,
     const float* __restrict__ means, const float* __restrict__ stdev,
     unsigned short* __restrict__ hi, unsigned short* __restrict__ lo){
  __shared__ float tile[64][65];
  int b=blockIdx.z;
  int ct=blockIdx.x*64, lt=blockIdx.y*64;
  int tid=threadIdx.x;
  int i=tid>>2, j0=(tid&3)*16;
  {
    const float* src = xe + ((size_t)b*L_ + lt + i)*E_ + ct + j0;
    float tmp[16];
    *(float4*)&tmp[0]  = *(const float4*)(src);
    *(float4*)&tmp[4]  = *(const float4*)(src+4);
    *(float4*)&tmp[8]  = *(const float4*)(src+8);
    *(float4*)&tmp[12] = *(const float4*)(src+12);
    for(int j=0;j<16;j++) tile[i][j0+j]=tmp[j];
  }
  __syncthreads();
  {
    float ms=means[b*E_+ct+i];
    float sd=stdev[b*E_+ct+i];
    unsigned short hs[16], ls[16];
    for(int j=0;j<16;j++){
      float v=(tile[j0+j][i]-ms)/sd;
      unsigned short hh=f2bf(v);
      hs[j]=hh; ls[j]=f2bf(v-bf2f(hh));
    }
    size_t off = ((size_t)b*NTOK + ct + i)*(size_t)L_ + lt + j0;
    *(uint4*)&hi[off]   = *(uint4*)&hs[0];
    *(uint4*)&hi[off+8] = *(uint4*)&hs[8];
    *(uint4*)&lo[off]   = *(uint4*)&ls[0];
    *(uint4*)&lo[off+8] = *(uint4*)&ls[8];
  }
}

__global__ void k_pack_marks(const float* __restrict__ xm,
    unsigned short* __restrict__ hi, unsigned short* __restrict__ lo){
  int idx=blockIdx.x*256+threadIdx.x; // 32*4*512
  int l=idx&511, j=(idx>>9)&3, b=idx>>11;
  float v = xm[((size_t)b*L_ + l)*NMARK_ + j];
  unsigned short hh=f2bf(v);
  size_t off=((size_t)b*NTOK + E_ + j)*(size_t)L_ + l;
  hi[off]=hh; lo[off]=f2bf(v-bf2f(hh));
}

// ------ 128x128 bf16 MFMA GEMM ----------------------------------------------
// XCD-chunked block swizzle + both-sides LDS XOR bank swizzle.
// AFULL=true  (BFULL ignored=true): hi tiles dbuf, lo tiles single; 3 MFMAs;
//             48KB. AFULL=false,BFULL=true: 3 tiles dbuf, 2 MFMAs, 48KB.
// AFULL=false,BFULL=false: 2 tiles (Ahi,Bhi) dbuf, 1 MFMA, 32KB -> 5 blk/CU.
// OUTMODE 0: fp32 C. 3: relu + bf16-hi only.
// TPADDED: M rows indexed b*520+t, A from compact [b*516+t], t>=516 -> zeropad.
template<int OUTMODE, bool TPADDED, bool AFULL, bool BFULL>
__global__ __launch_bounds__(256) void k_gemm(
    const unsigned short* __restrict__ Ahi, const unsigned short* __restrict__ Alo,
    const unsigned short* __restrict__ Bhi, const unsigned short* __restrict__ Blo,
    const float* __restrict__ bias, float* __restrict__ Cf,
    unsigned short* __restrict__ Chi, unsigned short* __restrict__ Clo,
    const unsigned short* __restrict__ zeropad,
    int M, int N, int K)
{
  constexpr int NT3 = BFULL ? 3 : 2;               // tiles in non-AFULL path
  constexpr int NLDSROWS = AFULL ? 6 : 2*NT3;      // 6 / 6 / 4
  __shared__ __align__(16) unsigned short LDS[NLDSROWS][128*32];
  // ---- XCD-chunked swizzle (bijective, any grid size; m204 form) ----
  int flat = blockIdx.y*gridDim.x + blockIdx.x;
  int ntot = gridDim.x*gridDim.y;
  int q = ntot>>3, r = ntot&7;
  int xcd = flat&7, jj = flat>>3;
  int f2 = xcd*q + (xcd<r?xcd:r) + jj;
  const int m0=(f2/(int)gridDim.x)*128, n0=(f2%(int)gridDim.x)*128;
  const int tid=threadIdx.x, lane=tid&63, wave=tid>>6;
  const int wm=(wave>>1)*64, wn=(wave&1)*64;

  // wave->tile: AFULL: 0=Ahi 1=Alo 2=Bhi 3=Blo ; BFULL: 0=Ahi 1=Bhi 2=Blo ;
  // else: 0=Ahi 1=Bhi. Stage: call j covers rows j*16..j*16+15.
  // Bank swizzle: lane loads global 16B-slot ((i&3) ^ (row&3)); LDS dest
  // stays linear (gload_lds constraint); reads XOR the same bits back.
  const unsigned short* srcp;
  bool isA;
  if constexpr (AFULL){
    srcp = (wave==0)?Ahi:(wave==1)?Alo:(wave==2)?Bhi:Blo;
    isA  = (wave<2);
  } else if constexpr (BFULL){
    srcp = (wave==0)?Ahi:(wave==1)?Bhi:Blo;   // wave 3 idles
    isA  = (wave==0);
  } else {
    srcp = (wave==0)?Ahi:Bhi;                 // waves 2,3 idle in staging
    isA  = (wave==0);
  }
  const bool stager = AFULL || (wave<NT3);
  const int rsub=lane>>2, seg=(((lane&3)^(rsub&3)))*8;   // source permute
  const unsigned short* gp[8]; int stp[8];
  #pragma unroll
  for(int j=0;j<8;j++){
    int row=j*16+rsub;
    if(isA){
      size_t ao; bool valid=true;
      int g=m0+row;
      if constexpr (TPADDED){
        int b=g/TPAD; int t=g-b*TPAD; valid=(t<NTOK);
        ao=((size_t)b*NTOK + (valid?t:0))*(size_t)K;
      } else ao=(size_t)g*(size_t)K;
      gp[j]= valid ? (srcp+ao+seg) : (zeropad+seg);
      stp[j]= valid ? 32 : 0;
    } else {
      gp[j]= srcp + (size_t)(n0+row)*(size_t)K + seg;
      stp[j]=32;
    }
  }

  v4f acc[4][4];
  for(int i=0;i<4;i++)for(int j=0;j<4;j++) acc[i][j]=(v4f){0.f,0.f,0.f,0.f};
  const int am = wm + (lane&15);
  const int bn = wn + (lane&15);
  const int kk = (lane>>4)*8;
  const int ka = kk ^ ((am&3)<<3);   // read-side XOR (A rows)
  const int kb = kk ^ ((bn&3)<<3);   // read-side XOR (B rows)
  const int nIter=K/32;

  if constexpr (AFULL){
    // prologue: wave0->Ahi buf0 (LDS0), wave2->Bhi buf0 (LDS1),
    //           wave1->Alo (LDS4), wave3->Blo (LDS5)
    {
      unsigned short* dst0 = (wave==0)?&LDS[0][0]:(wave==2)?&LDS[1][0]
                            :(wave==1)?&LDS[4][0]:&LDS[5][0];
      #pragma unroll
      for(int j=0;j<8;j++){ gload_lds16(gp[j], dst0+j*512); gp[j]+=stp[j]; }
    }
    for(int k=0;k<nIter;k++){
      __syncthreads();   // drains: hi buf[k&1] + lo(k) complete
      if(k+1<nIter && (wave==0||wave==2)){   // hi prefetch overlaps MFMAs
        unsigned short* nxt=&LDS[((k+1)&1)*2+(wave>>1)][0];
        #pragma unroll
        for(int j=0;j<8;j++){ gload_lds16(gp[j], nxt+j*512); gp[j]+=stp[j]; }
      }
      const unsigned short* curA =&LDS[(k&1)*2+0][0];
      const unsigned short* curB =&LDS[(k&1)*2+1][0];
      const unsigned short* curAl=&LDS[4][0];
      const unsigned short* curBl=&LDS[5][0];
      v8s a[4], al[4], b[4], bl[4];
      for(int t=0;t<4;t++){
        a[t] =*(const v8s*)&curA [(am+t*16)*32+ka];
        al[t]=*(const v8s*)&curAl[(am+t*16)*32+ka];
        b[t] =*(const v8s*)&curB [(bn+t*16)*32+kb];
        bl[t]=*(const v8s*)&curBl[(bn+t*16)*32+kb];
      }
      for(int mt=0;mt<4;mt++)for(int nt=0;nt<4;nt++){
        acc[mt][nt]=__builtin_amdgcn_mfma_f32_16x16x32_bf16(al[mt],b[nt], acc[mt][nt],0,0,0);
        acc[mt][nt]=__builtin_amdgcn_mfma_f32_16x16x32_bf16(a[mt], bl[nt],acc[mt][nt],0,0,0);
        acc[mt][nt]=__builtin_amdgcn_mfma_f32_16x16x32_bf16(a[mt], b[nt], acc[mt][nt],0,0,0);
      }
      if(k+1<nIter){     // k uniform -> barrier uniform
        __syncthreads(); // all waves done READING lo(k)
        if(wave==1||wave==3){   // re-stage lo(k+1) into the single buffer
          unsigned short* nxt=&LDS[4+(wave>>1)][0];
          #pragma unroll
          for(int j=0;j<8;j++){ gload_lds16(gp[j], nxt+j*512); gp[j]+=stp[j]; }
        }
      }
    }
  } else {
    // prologue: DMA tile 0 into buf 0 (tiles = LDS[buf*NT3 + t])
    if(stager){
      #pragma unroll
      for(int j=0;j<8;j++){ gload_lds16(gp[j], &LDS[wave][j*512]); gp[j]+=stp[j]; }
    }
    for(int k=0;k<nIter;k++){
      __syncthreads();   // buf[k&1] DMA complete
      if(k+1<nIter && stager){
        unsigned short* nxt=&LDS[((k+1)&1)*NT3+wave][0];
        #pragma unroll
        for(int j=0;j<8;j++){ gload_lds16(gp[j], nxt+j*512); gp[j]+=stp[j]; }
      }
      const unsigned short* curA =&LDS[(k&1)*NT3+0][0];
      const unsigned short* curB =&LDS[(k&1)*NT3+1][0];
      v8s a[4], b[4], bl[4];
      for(int t=0;t<4;t++){
        a[t] =*(const v8s*)&curA [(am+t*16)*32+ka];
        b[t] =*(const v8s*)&curB [(bn+t*16)*32+kb];
      }
      if constexpr (BFULL){
        const unsigned short* curBl=&LDS[(k&1)*NT3+2][0];
        for(int t=0;t<4;t++)
          bl[t]=*(const v8s*)&curBl[(bn+t*16)*32+kb];
      }
      for(int mt=0;mt<4;mt++)for(int nt=0;nt<4;nt++){
        if constexpr (BFULL)
          acc[mt][nt]=__builtin_amdgcn_mfma_f32_16x16x32_bf16(a[mt], bl[nt],acc[mt][nt],0,0,0);
        acc[mt][nt]=__builtin_amdgcn_mfma_f32_16x16x32_bf16(a[mt], b[nt], acc[mt][nt],0,0,0);
      }
    }
  }
  // C/D mapping: col=lane&15, row=(lane>>4)*4+r
  for(int mt=0;mt<4;mt++)for(int nt=0;nt<4;nt++){
    int col = n0 + wn + nt*16 + (lane&15);
    int rb  = m0 + wm + mt*16 + (lane>>4)*4;
    float bv = bias ? bias[col] : 0.f;
    for(int r2=0;r2<4;r2++){
      float v = acc[mt][nt][r2] + bv;
      size_t off=(size_t)(rb+r2)*N + col;
      if constexpr (OUTMODE==0){
        Cf[off]=v;
      } else {                            // OUTMODE==3: relu + hi-only bf16
        v = v>0.f ? v : 0.f;
        Chi[off]=f2bf(v);
      }
    }
  }
  (void)Clo;
}

// --- rot[f][h][i] (64 x 4 x 65) -> rT[h][tile][f][16] (i = tile*13+j, j<13) -
__global__ void k_rotTile(const float* __restrict__ rot, float* __restrict__ rT){
  int idx=blockIdx.x*256+threadIdx.x;   // 2 layers x 16640
  if(idx>=2*64*260) return;
  int lyr=idx/16640, r2=idx-lyr*16640;
  int f=r2/260, r=r2-f*260;             // r = h*65+i
  int h=r/65, i=r-h*65;
  int tile=i/13, j=i-tile*13;
  rT[(size_t)lyr*20800 + (((size_t)(h*5+tile)*64)+f)*16 + j]=rot[idx];
}

// ---------------- LSH buckets: wave=hash, thread=token, 5x13 output tiles ---
// (R13 version, best measured: 89us, VGPR 20, no spill.)
__global__ __launch_bounds__(256) void k_buckets(const float* __restrict__ qk,
    const float* __restrict__ rT, unsigned char* __restrict__ buckets){
  __shared__ float qkT[64*69];   // [f][t], stride 69 -> conflict-free
  int bh=blockIdx.x, tc=blockIdx.y;
  int b=bh>>3, hd=bh&7;
  int t0=tc*64;
  int tid=threadIdx.x;
  for(int j=tid;j<4096;j+=256){
    int t=j>>6, f=j&63;
    int tg=t0+t;
    qkT[f*69+t] = (tg<TPAD)? qk[((size_t)b*TPAD+tg)*(size_t)D_ + hd*64 + f] : 0.f;
  }
  __syncthreads();
  int h = __builtin_amdgcn_readfirstlane(tid>>6);   // wave-uniform hash
  int t = tid&63;
  float bv=-1.f; int bi=0x7fffffff;                 // cv >= 0 always
  #pragma unroll 1
  for(int tile=0; tile<5; ++tile){
    const float* rr = rT + ((size_t)(h*5+tile)*64)*16;  // wave-uniform
    float acc[13];
    #pragma unroll
    for(int j=0;j<13;j++) acc[j]=0.f;
    #pragma unroll 2
    for(int f=0;f<64;f++){
      float q = qkT[f*69+t];
      const float* rf = rr + f*16;
      #pragma unroll
      for(int j=0;j<13;j++) acc[j] += q*rf[j];
    }
    #pragma unroll
    for(int j=0;j<13;j++){
      int i = tile*13+j;
      float r=acc[j]; float cv; int ci;
      if(r>=-r){cv=r;ci=i;}else{cv=-r;ci=i+65;}
      if(cv>bv||(cv==bv&&ci<bi)){bv=cv;bi=ci;}
    }
  }
  int tg=t0+t;
  if(tg<TPAD) buckets[((size_t)bh*4+h)*TPAD+tg]=(unsigned char)bi;
}

// ---------------- stable counting sort == jnp.argsort(bucket*t+pos) ---------
__global__ __launch_bounds__(64) void k_sort(const unsigned char* __restrict__ buckets,
    unsigned short* __restrict__ sticker, unsigned short* __restrict__ undo){
  __shared__ int cnt[520];
  __shared__ int offs[520];
  int bh=blockIdx.x, tid=threadIdx.x;
  const unsigned char* bb = buckets + (size_t)bh*4*TPAD;
  for(int i=tid;i<520;i+=64) cnt[i]=0;
  __syncthreads();
  for(int i=tid;i<2080;i+=64){
    int h=i/TPAD;
    atomicAdd(&cnt[(int)bb[i]+h*NB_],1);
  }
  __syncthreads();
  if(tid==0){ int s=0; for(int k2=0;k2<520;k2++){ offs[k2]=s; s+=cnt[k2]; } }
  __syncthreads();
  if(tid<4){
    int h=tid;
    unsigned short* stk = sticker + (size_t)bh*2080;
    unsigned short* ud  = undo    + (size_t)bh*2080;
    for(int p=0;p<TPAD;p++){
      int key = (int)bb[h*TPAD+p] + h*NB_;
      int j = offs[key]++;
      stk[j] = (unsigned short)(h*TPAD+p);
      ud[h*TPAD+p] = (unsigned short)j;
    }
  }
}

// -------- attention pass 1: per-chunk LSE + store masked dots into PR -------
__global__ __launch_bounds__(256) void k_attn1(const float* __restrict__ qk,
    const unsigned short* __restrict__ sticker, float* __restrict__ lse,
    float* __restrict__ PR){
  __shared__ float rows[8][8][68];
  __shared__ int   sts[8][8];
  __shared__ float n2s[8][8];
  int tid=threadIdx.x, grp=tid>>5, lane=tid&31;
  int gid=blockIdx.x*8+grp;
  int bh=gid/NCH_, c=gid-bh*NCH_;
  int b=bh>>3, hd=bh&7;
  const unsigned short* stk = sticker + (size_t)bh*2080;
  if(lane<8){
    int r=lane;
    int cprev=(c+NCH_-1)%NCH_;
    int j=(r<4)? c*4+r : cprev*4+(r-4);
    sts[grp][r]=(int)stk[j]%TPAD;
  }
  __syncthreads();
  #pragma unroll
  for(int it=0; it<2; it++){
    int j=lane+32*it;
    int r=j>>3, f0=(j&7)*8;
    const float* src=qk+((size_t)b*TPAD+sts[grp][r])*(size_t)D_+hd*64+f0;
    *(float4*)&rows[grp][r][f0]   = *(const float4*)src;
    *(float4*)&rows[grp][r][f0+4] = *(const float4*)(src+4);
  }
  __syncthreads();
  {
    int r=lane>>2, part=lane&3;
    float s=0.f;
    #pragma unroll
    for(int f=part*16; f<part*16+16; f++){ float v=rows[grp][r][f]; s+=v*v; }
    s+=__shfl_xor(s,1,64); s+=__shfl_xor(s,2,64);
    if(part==0) n2s[grp][r]=s;
  }
  __syncthreads();
  int qi=lane>>3, kj=lane&7;
  float dt=0.f;
  #pragma unroll
  for(int f=0;f<64;f++) dt += rows[grp][qi][f]*rows[grp][kj][f];
  float kn=n2s[grp][kj]; kn = kn>1e-24f? kn:1e-24f;
  dt = dt/sqrtf(kn)*0.125f;
  if(sts[grp][qi]==sts[grp][kj]) dt=-5e4f;
  PR[((size_t)bh*2080 + c*4 + qi)*8 + kj] = dt;
  float mx=dt;
  for(int o=1;o<8;o<<=1){ float om=__shfl_xor(mx,o,64); mx=om>mx?om:mx; }
  float sm=expf(dt-mx);
  for(int o=1;o<8;o<<=1) sm+=__shfl_xor(sm,o,64);
  if(kj==0) lse[(size_t)bh*2080 + c*4 + qi] = mx + logf(sm);
}

// ---- dots -> probs (in-place in PR); per-token LSE over 4 rounds inlined ---
__global__ void k_probs(const float* __restrict__ lse, const unsigned short* __restrict__ sticker,
    const unsigned short* __restrict__ undo, float* __restrict__ PR){
  int j=blockIdx.x*256+threadIdx.x;     // BH*2080 slots
  if(j>=BH_*2080) return;
  int bh=j/2080;
  const unsigned short* u=undo+(size_t)bh*2080;
  const float* ls=lse+(size_t)bh*2080;
  float L=lse[j];
  int p=(int)sticker[j]%TPAD;
  float l0=ls[u[p]], l1=ls[u[TPAD+p]], l2=ls[u[2*TPAD+p]], l3=ls[u[3*TPAD+p]];
  float mx=fmaxf(fmaxf(l0,l1),fmaxf(l2,l3));
  float lt=mx+logf(expf(l0-mx)+expf(l1-mx)+expf(l2-mx)+expf(l3-mx));
  float w=expf(L-lt);
  float* pr=PR+(size_t)j*8;
  float4 d0=*(float4*)pr, d1=*(float4*)(pr+4);
  d0.x=expf(d0.x-L)*w; d0.y=expf(d0.y-L)*w; d0.z=expf(d0.z-L)*w; d0.w=expf(d0.w-L)*w;
  d1.x=expf(d1.x-L)*w; d1.y=expf(d1.y-L)*w; d1.z=expf(d1.z-L)*w; d1.w=expf(d1.w-L)*w;
  *(float4*)pr=d0; *(float4*)(pr+4)=d1;
}

// ------- attention gather: out[b,t,:] = sum P*v, split-write hi/lo ----------
__global__ __launch_bounds__(256) void k_gather(const float* __restrict__ v,
    const unsigned short* __restrict__ sticker, const unsigned short* __restrict__ undo,
    const float* __restrict__ PR, unsigned short* __restrict__ ahi,
    unsigned short* __restrict__ alo){
  __shared__ int   ridx[8][32];
  __shared__ float pval[8][32];
  int b=blockIdx.x, t=blockIdx.y;
  int tid=threadIdx.x, hd=tid>>5, l=tid&31;
  int bh=b*8+hd;
  const unsigned short* stk = sticker + (size_t)bh*2080;
  const unsigned short* ud  = undo    + (size_t)bh*2080;
  {
    int h=l>>3, kj=l&7;
    int j = (int)ud[h*TPAD+t];
    int c = j>>2;
    int slot = (kj<4)? (c*4+kj) : (((c+NCH_-1)%NCH_)*4 + (kj-4));
    ridx[hd][l] = (int)stk[slot]%TPAD;
    pval[hd][l] = PR[((size_t)bh*2080 + j)*8 + kj];
  }
  __syncthreads();
  int f0=l*2;
  float a0=0.f, a1=0.f;
  const float* vb = v + (size_t)b*TPAD*D_ + hd*64 + f0;
  for(int i=0;i<32;i++){
    const float* vr = vb + (size_t)ridx[hd][i]*D_;
    float p=pval[hd][i];
    a0 += p*vr[0];
    a1 += p*vr[1];
  }
  size_t off = ((size_t)b*NTOK + t)*(size_t)D_ + hd*64 + f0;
  unsigned short h0=f2bf(a0), h1=f2bf(a1);
  ahi[off]=h0; ahi[off+1]=h1;
  alo[off]=f2bf(a0-bf2f(h0)); alo[off+1]=f2bf(a1-bf2f(h1));
}

// -------- x = LN(x + delta)*g + b ; also split-write hi/lo ------------------
__global__ __launch_bounds__(256) void k_addln(float* __restrict__ x,
    const float* __restrict__ delta, const float* __restrict__ g,
    const float* __restrict__ bb, unsigned short* __restrict__ xhi,
    unsigned short* __restrict__ xlo){
  __shared__ float red[4];
  int row=blockIdx.x, tid=threadIdx.x;
  size_t base=(size_t)row*D_;
  float v0=x[base+tid]+delta[base+tid];
  float v1=x[base+tid+256]+delta[base+tid+256];
  float m=blockReduce256(v0+v1,red,tid)*(1.f/512.f);
  float d0=v0-m, d1=v1-m;
  float var=blockReduce256(d0*d0+d1*d1,red,tid)*(1.f/512.f);
  float inv=1.f/sqrtf(var+1e-5f);
  float y0=d0*inv*g[tid]    +bb[tid];
  float y1=d1*inv*g[tid+256]+bb[tid+256];
  x[base+tid]=y0; x[base+tid+256]=y1;
  unsigned short h0=f2bf(y0), h1=f2bf(y1);
  xhi[base+tid]=h0; xhi[base+tid+256]=h1;
  xlo[base+tid]=f2bf(y0-bf2f(h0)); xlo[base+tid+256]=f2bf(y1-bf2f(h1));
}

// ---------------- final LN on last token + projection -----------------------
__global__ __launch_bounds__(256) void k_dec(const float* __restrict__ x,
    const float* __restrict__ gF, const float* __restrict__ bF,
    const float* __restrict__ Wp, const float* __restrict__ bp,
    float* __restrict__ dec){
  __shared__ float red[4];
  int b=blockIdx.x, tid=threadIdx.x;
  const float* row = x + ((size_t)b*NTOK + (NTOK-1))*(size_t)D_;
  float v0=row[tid], v1=row[tid+256];
  float m=blockReduce256(v0+v1,red,tid)*(1.f/512.f);
  float d0=v0-m, d1=v1-m;
  float var=blockReduce256(d0*d0+d1*d1,red,tid)*(1.f/512.f);
  float inv=1.f/sqrtf(var+1e-5f);
  float y0=d0*inv*gF[tid]    +bF[tid];
  float y1=d1*inv*gF[tid+256]+bF[tid+256];
  float dd=blockReduce256(y0*Wp[tid]+y1*Wp[tid+256],red,tid);
  if(tid==0) dec[b]=dd+bp[0];
}

__global__ void k_out(const float* __restrict__ dec, const float* __restrict__ means,
    const float* __restrict__ stdev, float* __restrict__ out){
  int idx=blockIdx.x*256+threadIdx.x;
  int e=idx&511, j=(idx>>9)&31, i=idx>>14;
  out[idx]=dec[j]*stdev[i*E_+e]+means[i*E_+e];
}

// ============================================================================
extern "C" void kernel_launch(void* const* d_in, const int* in_sizes, int n_in,
                              void* d_out, int out_size, void* d_ws, size_t ws_size,
                              hipStream_t stream){
  (void)in_sizes; (void)n_in; (void)out_size;
  const float* xe   = (const float*)d_in[0];
  const float* xm   = (const float*)d_in[1];
  const float* Wemb = (const float*)d_in[2];
  const float* bemb = (const float*)d_in[3];
  const float* Wqk  = (const float*)d_in[4];
  const float* Wv   = (const float*)d_in[5];
  const float* Wo   = (const float*)d_in[6];
  const float* boP  = (const float*)d_in[7];
  const float* Wc1  = (const float*)d_in[8];
  const float* bc1  = (const float*)d_in[9];
  const float* Wc2  = (const float*)d_in[10];
  const float* bc2  = (const float*)d_in[11];
  const float* g1   = (const float*)d_in[12];
  const float* b1   = (const float*)d_in[13];
  const float* g2   = (const float*)d_in[14];
  const float* b2   = (const float*)d_in[15];
  const float* gF   = (const float*)d_in[16];
  const float* bF   = (const float*)d_in[17];
  const float* Wp   = (const float*)d_in[18];
  const float* bp   = (const float*)d_in[19];
  const float* rot  = (const float*)d_in[20];
  float* out = (float*)d_out;

  // ---- workspace carve ----
  char* w=(char*)d_ws;
  auto carve=[&](size_t n)->char*{ char* p=w; w += (n+255)&~(size_t)255; return p; };
  float* means=(float*)carve(65536);
  float* stdev=(float*)carve(65536);
  float* dec  =(float*)carve(256);
  unsigned short* zp=(unsigned short*)carve(512);              // zero page
  float* rT   =(float*)carve(166400);                          // 2 x [4][5][64][16] fp32
  float* x    =(float*)carve((size_t)B_*NTOK*D_*4);            // 33.8 MB
  unsigned short* xhi=(unsigned short*)carve((size_t)B_*NTOK*D_*2); // 16.9
  unsigned short* xlo=(unsigned short*)carve((size_t)B_*NTOK*D_*2); // 16.9
  float* BIG  =(float*)carve((size_t)B_*TPAD*D_*4);            // 34.1 (qk/v/delta)
  constexpr size_t WTOT=6029312;
  unsigned short* whi=(unsigned short*)carve(WTOT*2);          // 12.1
  unsigned short* wlo=(unsigned short*)carve(WTOT*2);          // 12.1
  // Union arena: [PR|bkt|stk|ud|lse] (attention) vs [hid] (FFN).
  constexpr size_t UBASE=45088768;
  constexpr size_t UFULL=(size_t)16512*2048*2;                 // 67.6 MB
  size_t used=(size_t)(w-(char*)d_ws);
  bool fullffn = ws_size >= used + UFULL + 4096;
  char* U = carve(fullffn ? UFULL : UBASE);
  float*          PR    =(float*)U;                                   // 17.04 MB
  unsigned char*  bkt   =(unsigned char*) (U+17039360);               // 0.53
  unsigned short* stk   =(unsigned short*)(U+17039360+532480);        // 1.06
  unsigned short* ud    =(unsigned short*)(U+17039360+532480+1064960);// 1.06
  float*          lseB  =(float*)(U+17039360+532480+2129920);         // 2.13
  unsigned short* hidHi =(unsigned short*)U;                          // 34.1 or 67.6 MB

  hipMemsetAsync(zp,0,512,stream);

  // weight arena offsets (elements); per-layer strides
  constexpr size_t oWemb=0, oWqk=262144, oWv=786432, oWo=1310720,
                   oWc1=1835008, oWc2=3932160;
  constexpr size_t Wsz=262144, C1sz=1048576, C2sz=1048576;

  // ---- split weights once (n = TOTAL elements) ----
  k_split<<<(262144+255)/256,256,0,stream>>>(Wemb,whi+oWemb,wlo+oWemb,262144);
  k_split<<<(524288+255)/256,256,0,stream>>>(Wqk, whi+oWqk, wlo+oWqk, 524288);
  k_split<<<(524288+255)/256,256,0,stream>>>(Wv,  whi+oWv,  wlo+oWv,  524288);
  k_split<<<(524288+255)/256,256,0,stream>>>(Wo,  whi+oWo,  wlo+oWo,  524288);
  k_split<<<(2097152+255)/256,256,0,stream>>>(Wc1, whi+oWc1, wlo+oWc1, 2097152);
  k_split<<<(2097152+255)/256,256,0,stream>>>(Wc2, whi+oWc2, wlo+oWc2, 2097152);
  k_rotTile<<<(2*16640+255)/256,256,0,stream>>>(rot,rT);   // both layers

  // ---- embedding: GEMM writes x (no alias), then split x -> xhi/xlo ----
  k_revin<<<dim3(2,B_),256,0,stream>>>(xe,means,stdev);
  k_pack_tok<<<dim3(8,8,B_),256,0,stream>>>(xe,means,stdev,xhi,xlo);
  k_pack_marks<<<(B_*NMARK_*L_)/256,256,0,stream>>>(xm,xhi,xlo);
  k_gemm<0,false,true,true><<<dim3(4,129),256,0,stream>>>(xhi,xlo,whi+oWemb,wlo+oWemb,bemb,x,nullptr,nullptr,zp,16512,512,512);
  k_split<<<(B_*NTOK*D_+255)/256,256,0,stream>>>(x,xhi,xlo,B_*NTOK*D_);

  for(int l=0;l<NLAYERS_;l++){
    const unsigned short* Wqk_h=whi+oWqk+(size_t)l*Wsz, *Wqk_l2=wlo+oWqk+(size_t)l*Wsz;
    const unsigned short* Wv_h =whi+oWv +(size_t)l*Wsz, *Wv_l2 =wlo+oWv +(size_t)l*Wsz;
    const unsigned short* Wo_h =whi+oWo +(size_t)l*Wsz, *Wo_l2 =wlo+oWo +(size_t)l*Wsz;
    const unsigned short* Wc1_h=whi+oWc1+(size_t)l*C1sz,*Wc1_l2=wlo+oWc1+(size_t)l*C1sz;
    const unsigned short* Wc2_h=whi+oWc2+(size_t)l*C2sz;
    const float* bo_l =boP+(size_t)l*D_;
    const float* bc1_l=bc1+(size_t)l*DFF_;
    const float* bc2_l=bc2+(size_t)l*D_;
    const float* g1_l=g1+(size_t)l*D_;
    const float* b1_l=b1+(size_t)l*D_;
    const float* g2_l=g2+(size_t)l*D_;
    const float* b2_l=b2+(size_t)l*D_;
    const float* rT_l=rT+(size_t)l*20800;

    // qk projection (FULL precision hi/lo, hybrid-buffered 48KB -> 1 round)
    k_gemm<0,true,true,true><<<dim3(4,130),256,0,stream>>>(xhi,xlo,Wqk_h,Wqk_l2,nullptr,BIG,nullptr,nullptr,zp,16640,512,512);
    // LSH routing + exact stable sort
    k_buckets<<<dim3(BH_,9),256,0,stream>>>(BIG,rT_l,bkt);
    k_sort<<<BH_,64,0,stream>>>(bkt,stk,ud);
    // LSE + dots (stored), then elementwise probs (wlse inlined)
    k_attn1<<<16640,256,0,stream>>>(BIG,stk,lseB,PR);
    k_probs<<<(BH_*2080+255)/256,256,0,stream>>>(lseB,stk,ud,PR);
    // v projection (A = xhi only: 2 MFMAs, dropped xlo@Wv ~2^-9 rel)
    k_gemm<0,true,false,true><<<dim3(4,130),256,0,stream>>>(xhi,zp,Wv_h,Wv_l2,nullptr,BIG,nullptr,nullptr,zp,16640,512,512);
    k_gather<<<dim3(B_,NTOK),256,0,stream>>>(BIG,stk,ud,PR,xhi,xlo);
    // output projection (A = attn-out hi only)
    k_gemm<0,false,false,true><<<dim3(4,129),256,0,stream>>>(xhi,zp,Wo_h,Wo_l2,bo_l,BIG,nullptr,nullptr,zp,16512,512,512);
    k_addln<<<16512,256,0,stream>>>(x,BIG,g1_l,b1_l,xhi,xlo);
    // FFN. Hidden = bf16 HI only (OUTMODE=3); c1: 2 MFMAs (Wc1 hi+lo);
    // c2: BFULL=false -> Wc2-hi only, 1 MFMA, 32KB LDS (5 blk/CU).
    if(fullffn){
      k_gemm<3,false,false,true ><<<dim3(16,129),256,0,stream>>>(xhi,zp,Wc1_h,Wc1_l2,bc1_l,nullptr,hidHi,nullptr,zp,16512,2048,512);
      k_gemm<0,false,false,false><<<dim3(4,129),256,0,stream>>>(hidHi,zp,Wc2_h,zp,bc2_l,BIG,nullptr,nullptr,zp,16512,512,2048);
    } else {
      const int rows0[2]={0,8320}, mrows[2]={8320,8192}, rblk[2]={65,64};
      for(int ch=0; ch<2; ch++){
        size_t rs=(size_t)rows0[ch];
        k_gemm<3,false,false,true ><<<dim3(16,rblk[ch]),256,0,stream>>>(xhi+rs*D_,zp,Wc1_h,Wc1_l2,bc1_l,nullptr,hidHi,nullptr,zp,mrows[ch],2048,512);
        k_gemm<0,false,false,false><<<dim3(4,rblk[ch]),256,0,stream>>>(hidHi,zp,Wc2_h,zp,bc2_l,BIG+rs*D_,nullptr,nullptr,zp,mrows[ch],512,2048);
      }
    }
    k_addln<<<16512,256,0,stream>>>(x,BIG,g2_l,b2_l,xhi,xlo);
  }

  k_dec<<<B_,256,0,stream>>>(x,gF,bF,Wp,bp,dec);
  k_out<<<2048,256,0,stream>>>(dec,means,stdev,out);
}